// Round 20
// baseline (309.528 us; speedup 1.0000x reference)
//
#include <hip/hip_runtime.h>

constexpr int H  = 16;
constexpr int HD = 48;
constexpr int D  = 768;    // H*HD
constexpr int DZ = 128;
constexpr int S  = 1024;
constexpr float EPS = 1e-5f;

typedef __attribute__((ext_vector_type(8))) short bf16x8;
typedef __attribute__((ext_vector_type(4))) float f32x4;

__device__ __forceinline__ float sigmoidf_(float x) { return 1.f / (1.f + __expf(-x)); }

__device__ __forceinline__ unsigned short f2b(float f) {
  unsigned u = __float_as_uint(f);
  u += 0x7FFFu + ((u >> 16) & 1u);
  return (unsigned short)(u >> 16);
}
__device__ __forceinline__ void split2(float x, unsigned short& h, unsigned short& l) {
  const unsigned short hb = f2b(x);
  const float hf = __uint_as_float((unsigned)hb << 16);
  h = hb;
  l = f2b(x - hf);
}
__device__ __forceinline__ unsigned pack2(unsigned short a, unsigned short b) {
  return (unsigned)a | ((unsigned)b << 16);
}

// ===========================================================================
// prep: split6 + pb_prep (block 768,y0) + padzero (blocks 769..).
// grid dim3(812, 6).
// ===========================================================================
__global__ __launch_bounds__(256)
void prep_kernel(const float* __restrict__ s, const float* __restrict__ Wq,
                 const float* __restrict__ Wk, const float* __restrict__ Wv,
                 const float* __restrict__ Wg, const float* __restrict__ Wo,
                 unsigned short* __restrict__ s_hi, unsigned short* __restrict__ s_lo,
                 unsigned short* __restrict__ w_hi, unsigned short* __restrict__ w_lo,
                 const float* __restrict__ Wz, const float* __restrict__ ln_w,
                 const float* __restrict__ ln_b, unsigned short* __restrict__ wzwb,
                 float* __restrict__ s12,
                 unsigned short* __restrict__ q_hi, unsigned short* __restrict__ q_lo,
                 unsigned short* __restrict__ k_hi, unsigned short* __restrict__ k_lo) {
  if (blockIdx.x >= 769) {
    const int pid = (blockIdx.x - 769) * 6 + blockIdx.y;
    if (pid < 256) {
      const int i = pid * 256 + threadIdx.x;     // < 65536
      const int row = i >> 6, rem = i & 63;
      const int h = rem >> 2, off = (rem & 3) << 2;
      const size_t a = (size_t)row * 1024 + h * 64 + 48 + off;
      const ushort4 zz = {0, 0, 0, 0};
      *reinterpret_cast<ushort4*>(q_hi + a) = zz;
      *reinterpret_cast<ushort4*>(q_lo + a) = zz;
      *reinterpret_cast<ushort4*>(k_hi + a) = zz;
      *reinterpret_cast<ushort4*>(k_lo + a) = zz;
    }
    return;
  }
  if (blockIdx.x == 768) {
    if (blockIdx.y != 0) return;
    const int t = threadIdx.x;
    for (int e = t; e < 16 * DZ; e += 256) wzwb[e] = f2b(Wz[e] * ln_w[e & 127]);
    __syncthreads();
    if (t < 32) {
      const int h = t & 15;
      float a = 0.f;
      if (t < 16) {
        for (int c = 0; c < DZ; ++c) {
          const unsigned u = (unsigned)wzwb[h * DZ + c] << 16;
          a += __uint_as_float(u);
        }
      } else {
        for (int c = 0; c < DZ; ++c) a += Wz[h * DZ + c] * ln_b[c];
      }
      s12[t] = a;
    }
    return;
  }
  const int seg = blockIdx.y;
  const float* src;
  unsigned short *dh, *dl;
  int n;
  if (seg == 0) { src = s; dh = s_hi; dl = s_lo; n = S * D; }
  else {
    src = (seg == 1) ? Wq : (seg == 2) ? Wk : (seg == 3) ? Wv : (seg == 4) ? Wg : Wo;
    dh = w_hi + (size_t)(seg - 1) * D * D;
    dl = w_lo + (size_t)(seg - 1) * D * D;
    n = D * D;
  }
  const int i4 = blockIdx.x * 256 + threadIdx.x;
  if (i4 * 4 < n) {
    const float4 v = *reinterpret_cast<const float4*>(src + (size_t)i4 * 4);
    ushort4 hh, ll;
    split2(v.x, hh.x, ll.x); split2(v.y, hh.y, ll.y);
    split2(v.z, hh.z, ll.z); split2(v.w, hh.w, ll.w);
    *reinterpret_cast<ushort4*>(dh + (size_t)i4 * 4) = hh;
    *reinterpret_cast<ushort4*>(dl + (size_t)i4 * 4) = ll;
  }
}

// ---------------------------------------------------------------------------
// Split-bf16 MFMA GEMM core over K range [k0,k1) (32x32 tile/wave).
// ---------------------------------------------------------------------------
__device__ __forceinline__ void mfma_core32(const unsigned short* __restrict__ Ah,
                                            const unsigned short* __restrict__ Al,
                                            const unsigned short* __restrict__ Wh,
                                            const unsigned short* __restrict__ Wl,
                                            const int m0, const int n0,
                                            const int k0, const int k1,
                                            f32x4& a00, f32x4& a01, f32x4& a10, f32x4& a11) {
  const int lane = threadIdx.x & 63;
  const int r16 = lane & 15, kg = lane >> 4;
  const unsigned short* pah = Ah + (size_t)(m0 + r16) * D + kg * 8;
  const unsigned short* pal = Al + (size_t)(m0 + r16) * D + kg * 8;
  const unsigned short* pbh = Wh + (size_t)(n0 + r16) * D + kg * 8;
  const unsigned short* pbl = Wl + (size_t)(n0 + r16) * D + kg * 8;
#pragma unroll 2
  for (int k = k0; k < k1; k += 32) {
    const bf16x8 ah0 = *reinterpret_cast<const bf16x8*>(pah + k);
    const bf16x8 ah1 = *reinterpret_cast<const bf16x8*>(pah + 16 * D + k);
    const bf16x8 al0 = *reinterpret_cast<const bf16x8*>(pal + k);
    const bf16x8 al1 = *reinterpret_cast<const bf16x8*>(pal + 16 * D + k);
    const bf16x8 bh0 = *reinterpret_cast<const bf16x8*>(pbh + k);
    const bf16x8 bh1 = *reinterpret_cast<const bf16x8*>(pbh + 16 * D + k);
    const bf16x8 bl0 = *reinterpret_cast<const bf16x8*>(pbl + k);
    const bf16x8 bl1 = *reinterpret_cast<const bf16x8*>(pbl + 16 * D + k);
    a00 = __builtin_amdgcn_mfma_f32_16x16x32_bf16(ah0, bh0, a00, 0, 0, 0);
    a00 = __builtin_amdgcn_mfma_f32_16x16x32_bf16(ah0, bl0, a00, 0, 0, 0);
    a00 = __builtin_amdgcn_mfma_f32_16x16x32_bf16(al0, bh0, a00, 0, 0, 0);
    a01 = __builtin_amdgcn_mfma_f32_16x16x32_bf16(ah0, bh1, a01, 0, 0, 0);
    a01 = __builtin_amdgcn_mfma_f32_16x16x32_bf16(ah0, bl1, a01, 0, 0, 0);
    a01 = __builtin_amdgcn_mfma_f32_16x16x32_bf16(al0, bh1, a01, 0, 0, 0);
    a10 = __builtin_amdgcn_mfma_f32_16x16x32_bf16(ah1, bh0, a10, 0, 0, 0);
    a10 = __builtin_amdgcn_mfma_f32_16x16x32_bf16(ah1, bl0, a10, 0, 0, 0);
    a10 = __builtin_amdgcn_mfma_f32_16x16x32_bf16(al1, bh0, a10, 0, 0, 0);
    a11 = __builtin_amdgcn_mfma_f32_16x16x32_bf16(ah1, bh1, a11, 0, 0, 0);
    a11 = __builtin_amdgcn_mfma_f32_16x16x32_bf16(ah1, bl1, a11, 0, 0, 0);
    a11 = __builtin_amdgcn_mfma_f32_16x16x32_bf16(al1, bh1, a11, 0, 0, 0);
  }
}

// ===========================================================================
// qkvg v3: split-K x2. Block = 4 waves = 2 tiles x 2 K-halves. 1536 blocks
// -> 6144 waves = 6/SIMD (was 3, grid-limited) to raise MLP on the cold
// weight stream (round-19 diagnosis: cold-latency-bound). Odd wave deposits
// partial accs to LDS [64][17] (stride 17 -> conflict-free), even wave adds
// and runs the (unchanged) corner-turn epilogue.
// ===========================================================================
__global__ __launch_bounds__(256)
void qkvg_mfma_kernel(const unsigned short* __restrict__ s_hi,
                      const unsigned short* __restrict__ s_lo,
                      const unsigned short* __restrict__ w_hi,
                      const unsigned short* __restrict__ w_lo,
                      const float* __restrict__ bq,
                      unsigned short* __restrict__ q_hi, unsigned short* __restrict__ q_lo,
                      unsigned short* __restrict__ k_hi, unsigned short* __restrict__ k_lo,
                      unsigned short* __restrict__ vt_hi, unsigned short* __restrict__ vt_lo,
                      float* __restrict__ g_ws) {
  __shared__ float TT[4][32 * 33];
  __shared__ float CB[2][64][17];
  const int wv = threadIdx.x >> 6;
  const int pair = wv >> 1;            // tile slot in block (0..1)
  const int khalf = wv & 1;
  const int tileid = blockIdx.x * 2 + pair;   // 0..3071
  const int wsel = tileid / 768;
  const int rr = tileid % 768;
  const int m0 = (rr / 24) * 32, n0 = (rr % 24) * 32;
  f32x4 a00 = {0.f, 0.f, 0.f, 0.f}, a01 = a00, a10 = a00, a11 = a00;
  mfma_core32(s_hi, s_lo, w_hi + (size_t)wsel * D * D, w_lo + (size_t)wsel * D * D,
              m0, n0, khalf * 384, khalf * 384 + 384, a00, a01, a10, a11);
  const int lane = threadIdx.x & 63;
  const int r16 = lane & 15, kg = lane >> 4;
  const float scale = 0.14433756729740643f;  // 1/sqrt(48)

  // combine K-halves: odd wave -> LDS, even wave adds
  if (khalf == 1) {
#pragma unroll
    for (int r = 0; r < 4; ++r) {
      CB[pair][lane][r] = a00[r];
      CB[pair][lane][4 + r] = a01[r];
      CB[pair][lane][8 + r] = a10[r];
      CB[pair][lane][12 + r] = a11[r];
    }
  }
  __syncthreads();
  if (khalf == 1) return;
#pragma unroll
  for (int r = 0; r < 4; ++r) {
    a00[r] += CB[pair][lane][r];
    a01[r] += CB[pair][lane][4 + r];
    a10[r] += CB[pair][lane][8 + r];
    a11[r] += CB[pair][lane][12 + r];
  }

  float* T = TT[wv];
#pragma unroll
  for (int r = 0; r < 4; ++r) {
    T[(kg * 4 + r) * 33 + r16] = a00[r];
    T[(kg * 4 + r) * 33 + 16 + r16] = a01[r];
    T[(16 + kg * 4 + r) * 33 + r16] = a10[r];
    T[(16 + kg * 4 + r) * 33 + 16 + r16] = a11[r];
  }
  const int rr2 = lane >> 1, run = lane & 1;
  if (wsel <= 1) {
    const int row = m0 + rr2;
    const int col0 = n0 + run * 16;
    const int hcol0 = (col0 / 48) * 64 + (col0 % 48);
    unsigned short* dh = (wsel == 0) ? q_hi : k_hi;
    unsigned short* dl = (wsel == 0) ? q_lo : k_lo;
#pragma unroll
    for (int p4 = 0; p4 < 4; ++p4) {
      unsigned short h0, l0, h1, l1, h2, l2, h3, l3;
      float v0 = T[rr2 * 33 + run * 16 + p4 * 4 + 0];
      float v1 = T[rr2 * 33 + run * 16 + p4 * 4 + 1];
      float v2 = T[rr2 * 33 + run * 16 + p4 * 4 + 2];
      float v3 = T[rr2 * 33 + run * 16 + p4 * 4 + 3];
      if (wsel == 0) {
        v0 = (v0 + bq[col0 + p4 * 4 + 0]) * scale;
        v1 = (v1 + bq[col0 + p4 * 4 + 1]) * scale;
        v2 = (v2 + bq[col0 + p4 * 4 + 2]) * scale;
        v3 = (v3 + bq[col0 + p4 * 4 + 3]) * scale;
      }
      split2(v0, h0, l0); split2(v1, h1, l1); split2(v2, h2, l2); split2(v3, h3, l3);
      uint2 uh, ul;
      uh.x = pack2(h0, h1); uh.y = pack2(h2, h3);
      ul.x = pack2(l0, l1); ul.y = pack2(l2, l3);
      *reinterpret_cast<uint2*>(dh + (size_t)row * 1024 + hcol0 + p4 * 4) = uh;
      *reinterpret_cast<uint2*>(dl + (size_t)row * 1024 + hcol0 + p4 * 4) = ul;
    }
  } else if (wsel == 2) {
    const int c = lane >> 1;
    const int run2 = lane & 1;
    const int vc = n0 + c;
#pragma unroll
    for (int p4 = 0; p4 < 4; ++p4) {
      unsigned short h0, l0, h1, l1, h2, l2, h3, l3;
      split2(T[(run2 * 16 + p4 * 4 + 0) * 33 + c], h0, l0);
      split2(T[(run2 * 16 + p4 * 4 + 1) * 33 + c], h1, l1);
      split2(T[(run2 * 16 + p4 * 4 + 2) * 33 + c], h2, l2);
      split2(T[(run2 * 16 + p4 * 4 + 3) * 33 + c], h3, l3);
      uint2 uh, ul;
      uh.x = pack2(h0, h1); uh.y = pack2(h2, h3);
      ul.x = pack2(l0, l1); ul.y = pack2(l2, l3);
      *reinterpret_cast<uint2*>(vt_hi + (size_t)vc * 1024 + m0 + run2 * 16 + p4 * 4) = uh;
      *reinterpret_cast<uint2*>(vt_lo + (size_t)vc * 1024 + m0 + run2 * 16 + p4 * 4) = ul;
    }
  } else {
    const int row = m0 + rr2;
#pragma unroll
    for (int p4 = 0; p4 < 4; ++p4) {
      float4 v4;
      v4.x = T[rr2 * 33 + run * 16 + p4 * 4 + 0];
      v4.y = T[rr2 * 33 + run * 16 + p4 * 4 + 1];
      v4.z = T[rr2 * 33 + run * 16 + p4 * 4 + 2];
      v4.w = T[rr2 * 33 + run * 16 + p4 * 4 + 3];
      *reinterpret_cast<float4*>(g_ws + (size_t)row * D + n0 + run * 16 + p4 * 4) = v4;
    }
  }
}

// ---------------------------------------------------------------------------
// pair_bias (unchanged): MFMA z@WzW^T with LN folded into epilogue.
// ---------------------------------------------------------------------------
__global__ __launch_bounds__(256)
void pair_bias_kernel(const float* __restrict__ z, const unsigned short* __restrict__ wzwb,
                      const float* __restrict__ s12, float* __restrict__ bias_out) {
  __shared__ float T[4][64 * 17];
  const int tid = threadIdx.x;
  const int lane = tid & 63;
  const int wv = tid >> 6;
  const int hq = lane & 15;
  const int grp = lane >> 4;

  bf16x8 bf[4];
#pragma unroll
  for (int m = 0; m < 4; ++m)
    bf[m] = *reinterpret_cast<const bf16x8*>(wzwb + hq * DZ + m * 32 + grp * 8);
  const float S1h = s12[hq], S2h = s12[16 + hq];

  const int chunk = blockIdx.x * 4 + wv;
  const size_t p0 = (size_t)chunk * 64;
  float* Tw = &T[wv][0];

#pragma unroll 1
  for (int sub = 0; sub < 4; ++sub) {
    const float* zr = z + (p0 + sub * 16 + hq) * DZ + grp * 8;
    f32x4 acc = {0.f, 0.f, 0.f, 0.f};
    float s1 = 0.f, s2 = 0.f;
#pragma unroll
    for (int m = 0; m < 4; ++m) {
      const float4 a0 = *reinterpret_cast<const float4*>(zr + m * 32);
      const float4 a1 = *reinterpret_cast<const float4*>(zr + m * 32 + 4);
      s1 += (a0.x + a0.y) + (a0.z + a0.w) + (a1.x + a1.y) + (a1.z + a1.w);
      s2 = fmaf(a0.x, a0.x, fmaf(a0.y, a0.y, fmaf(a0.z, a0.z, fmaf(a0.w, a0.w, s2))));
      s2 = fmaf(a1.x, a1.x, fmaf(a1.y, a1.y, fmaf(a1.z, a1.z, fmaf(a1.w, a1.w, s2))));
      bf16x8 af;
      af[0] = (short)f2b(a0.x); af[1] = (short)f2b(a0.y);
      af[2] = (short)f2b(a0.z); af[3] = (short)f2b(a0.w);
      af[4] = (short)f2b(a1.x); af[5] = (short)f2b(a1.y);
      af[6] = (short)f2b(a1.z); af[7] = (short)f2b(a1.w);
      acc = __builtin_amdgcn_mfma_f32_16x16x32_bf16(af, bf[m], acc, 0, 0, 0);
    }
    s1 += __shfl_xor(s1, 16); s1 += __shfl_xor(s1, 32);
    s2 += __shfl_xor(s2, 16); s2 += __shfl_xor(s2, 32);
    const float mu = s1 * (1.f / DZ);
    const float inv = rsqrtf(s2 * (1.f / DZ) - mu * mu + EPS);
#pragma unroll
    for (int r = 0; r < 4; ++r) {
      const int st = grp * 4 + r;
      const float mur = __shfl(mu, st);
      const float invr = __shfl(inv, st);
      Tw[(sub * 16 + st) * 17 + hq] = invr * (acc[r] - mur * S1h) + S2h;
    }
  }
#pragma unroll
  for (int hh = 0; hh < 16; ++hh)
    bias_out[(size_t)hh * S * S + p0 + lane] = Tw[lane * 17 + hh];
}

// ===========================================================================
// Attention v4 (unchanged from round 19): intra-block KV-split, fused reduce.
// ===========================================================================
constexpr int PST = 72;   // P slab stride (u16)
constexpr int PRS = 52;   // partial-result row stride (f32)

__global__ __launch_bounds__(256)
void attn_kernel(const unsigned short* __restrict__ q_hi, const unsigned short* __restrict__ q_lo,
                 const unsigned short* __restrict__ k_hi, const unsigned short* __restrict__ k_lo,
                 const unsigned short* __restrict__ vt_hi, const unsigned short* __restrict__ vt_lo,
                 const float* __restrict__ bias, const float* __restrict__ g,
                 unsigned short* __restrict__ a_hi, unsigned short* __restrict__ a_lo) {
  __shared__ unsigned short Ph[4][16 * PST], Pl[4][16 * PST];
  __shared__ float Pr[4][16 * PRS];
  const int lane = threadIdx.x & 63;
  const int wv = threadIdx.x >> 6;
  const int h = blockIdx.x >> 6;
  const int qb = blockIdx.x & 63;
  const int q0 = qb << 4;
  const int n16 = lane & 15, kg = lane >> 4;

  const size_t qbase = (size_t)(q0 + n16) * 1024 + h * 64;
  const bf16x8 qh0 = *reinterpret_cast<const bf16x8*>(q_hi + qbase + kg * 8);
  const bf16x8 qh1 = *reinterpret_cast<const bf16x8*>(q_hi + qbase + 32 + kg * 8);
  const bf16x8 ql0 = *reinterpret_cast<const bf16x8*>(q_lo + qbase + kg * 8);
  const bf16x8 ql1 = *reinterpret_cast<const bf16x8*>(q_lo + qbase + 32 + kg * 8);

  float mrow = -1e30f, lrow = 0.f;
  f32x4 accO[3] = {};
  unsigned short* php = Ph[wv];
  unsigned short* plp = Pl[wv];

#pragma unroll 1
  for (int t0 = wv * 256; t0 < wv * 256 + 256; t0 += 64) {
    f32x4 sc[4];
#pragma unroll
    for (int ts = 0; ts < 4; ++ts) {
      const size_t kb = (size_t)(t0 + ts * 16 + n16) * 1024 + h * 64;
      const bf16x8 kh0 = *reinterpret_cast<const bf16x8*>(k_hi + kb + kg * 8);
      const bf16x8 kh1 = *reinterpret_cast<const bf16x8*>(k_hi + kb + 32 + kg * 8);
      const bf16x8 kl0 = *reinterpret_cast<const bf16x8*>(k_lo + kb + kg * 8);
      const bf16x8 kl1 = *reinterpret_cast<const bf16x8*>(k_lo + kb + 32 + kg * 8);
      f32x4 a = *reinterpret_cast<const f32x4*>(
          bias + ((size_t)h * S + (q0 + n16)) * S + t0 + ts * 16 + kg * 4);
      a = __builtin_amdgcn_mfma_f32_16x16x32_bf16(kh0, qh0, a, 0, 0, 0);
      a = __builtin_amdgcn_mfma_f32_16x16x32_bf16(kh1, qh1, a, 0, 0, 0);
      a = __builtin_amdgcn_mfma_f32_16x16x32_bf16(kh0, ql0, a, 0, 0, 0);
      a = __builtin_amdgcn_mfma_f32_16x16x32_bf16(kh1, ql1, a, 0, 0, 0);
      a = __builtin_amdgcn_mfma_f32_16x16x32_bf16(kl0, qh0, a, 0, 0, 0);
      a = __builtin_amdgcn_mfma_f32_16x16x32_bf16(kl1, qh1, a, 0, 0, 0);
      sc[ts] = a;
    }

    float tmax = sc[0][0];
#pragma unroll
    for (int ts = 0; ts < 4; ++ts)
#pragma unroll
      for (int r = 0; r < 4; ++r) tmax = fmaxf(tmax, sc[ts][r]);
    tmax = fmaxf(tmax, __shfl_xor(tmax, 16));
    tmax = fmaxf(tmax, __shfl_xor(tmax, 32));
    const float mn = fmaxf(mrow, tmax);
    const float fac = __expf(mrow - mn);
    mrow = mn;
    float psum = 0.f;
#pragma unroll
    for (int ts = 0; ts < 4; ++ts) {
      const float p0_ = __expf(sc[ts][0] - mn), p1_ = __expf(sc[ts][1] - mn);
      const float p2_ = __expf(sc[ts][2] - mn), p3_ = __expf(sc[ts][3] - mn);
      psum += (p0_ + p1_) + (p2_ + p3_);
      unsigned short h0, l0, h1, l1, h2, l2, h3, l3;
      split2(p0_, h0, l0); split2(p1_, h1, l1); split2(p2_, h2, l2); split2(p3_, h3, l3);
      const int ti = ts * 16 + kg * 4;
      unsigned* wh = reinterpret_cast<unsigned*>(&php[n16 * PST + ti]);
      unsigned* wl = reinterpret_cast<unsigned*>(&plp[n16 * PST + ti]);
      wh[0] = pack2(h0, h1); wh[1] = pack2(h2, h3);
      wl[0] = pack2(l0, l1); wl[1] = pack2(l2, l3);
    }
    lrow = lrow * fac + psum;

    float facr[4];
#pragma unroll
    for (int r = 0; r < 4; ++r) facr[r] = __shfl(fac, kg * 4 + r);
#pragma unroll
    for (int ds = 0; ds < 3; ++ds)
#pragma unroll
      for (int r = 0; r < 4; ++r) accO[ds][r] *= facr[r];

#pragma unroll
    for (int c = 0; c < 2; ++c) {
      const bf16x8 pah = *reinterpret_cast<const bf16x8*>(&php[n16 * PST + c * 32 + kg * 8]);
      const bf16x8 pal = *reinterpret_cast<const bf16x8*>(&plp[n16 * PST + c * 32 + kg * 8]);
#pragma unroll
      for (int ds = 0; ds < 3; ++ds) {
        const size_t vb = (size_t)(h * 48 + ds * 16 + n16) * 1024 + t0 + c * 32 + kg * 8;
        const bf16x8 vh = *reinterpret_cast<const bf16x8*>(vt_hi + vb);
        const bf16x8 vl = *reinterpret_cast<const bf16x8*>(vt_lo + vb);
        accO[ds] = __builtin_amdgcn_mfma_f32_16x16x32_bf16(pah, vh, accO[ds], 0, 0, 0);
        accO[ds] = __builtin_amdgcn_mfma_f32_16x16x32_bf16(pah, vl, accO[ds], 0, 0, 0);
        accO[ds] = __builtin_amdgcn_mfma_f32_16x16x32_bf16(pal, vh, accO[ds], 0, 0, 0);
      }
    }
  }

  lrow += __shfl_xor(lrow, 16);
  lrow += __shfl_xor(lrow, 32);

  float* pw = Pr[wv];
#pragma unroll
  for (int ds = 0; ds < 3; ++ds)
#pragma unroll
    for (int r = 0; r < 4; ++r)
      pw[(kg * 4 + r) * PRS + ds * 16 + n16] = accO[ds][r];
  if (kg == 0) {
    pw[n16 * PRS + 48] = mrow;
    pw[n16 * PRS + 49] = lrow;
  }
  __syncthreads();

  const int row = threadIdx.x >> 4;
  const int dsub = threadIdx.x & 15;
  const float m0_ = Pr[0][row * PRS + 48], m1_ = Pr[1][row * PRS + 48];
  const float m2_ = Pr[2][row * PRS + 48], m3_ = Pr[3][row * PRS + 48];
  const float l0_ = Pr[0][row * PRS + 49], l1_ = Pr[1][row * PRS + 49];
  const float l2_ = Pr[2][row * PRS + 49], l3_ = Pr[3][row * PRS + 49];
  const float M = fmaxf(fmaxf(m0_, m1_), fmaxf(m2_, m3_));
  const float e0 = __expf(m0_ - M), e1 = __expf(m1_ - M);
  const float e2 = __expf(m2_ - M), e3 = __expf(m3_ - M);
  const float rl = 1.f / (l0_ * e0 + l1_ * e1 + l2_ * e2 + l3_ * e3);
#pragma unroll
  for (int j = 0; j < 3; ++j) {
    const int d = dsub * 3 + j;
    const float o = (Pr[0][row * PRS + d] * e0 + Pr[1][row * PRS + d] * e1 +
                     Pr[2][row * PRS + d] * e2 + Pr[3][row * PRS + d] * e3) * rl;
    const size_t idx = (size_t)(q0 + row) * D + h * 48 + d;
    const float a = o * sigmoidf_(g[idx]);
    unsigned short hh, ll;
    split2(a, hh, ll);
    a_hi[idx] = hh;
    a_lo[idx] = ll;
  }
}

// ===========================================================================
// outproj v3: split-K x2 on 32x16 tiles. Block = 4 waves = 2 tiles x 2
// K-halves; 768 blocks -> 3072 waves = 3/SIMD (was 1.5). LDS combine.
// ===========================================================================
__global__ __launch_bounds__(256)
void outproj_mfma_kernel(const unsigned short* __restrict__ a_hi,
                         const unsigned short* __restrict__ a_lo,
                         const unsigned short* __restrict__ w_hi,
                         const unsigned short* __restrict__ w_lo,
                         float* __restrict__ out) {
  __shared__ float CB[2][64][9];
  const int wv = threadIdx.x >> 6;
  const int pair = wv >> 1;
  const int khalf = wv & 1;
  const int tileid = blockIdx.x * 2 + pair;   // 0..1535
  const int m0 = (tileid / 48) * 32, n0 = (tileid % 48) * 16;
  const int lane = threadIdx.x & 63;
  const int r16 = lane & 15, kg = lane >> 4;
  const unsigned short* Wh = w_hi + (size_t)4 * D * D;
  const unsigned short* Wl = w_lo + (size_t)4 * D * D;
  const unsigned short* pah = a_hi + (size_t)(m0 + r16) * D + kg * 8;
  const unsigned short* pal = a_lo + (size_t)(m0 + r16) * D + kg * 8;
  const unsigned short* pbh = Wh + (size_t)(n0 + r16) * D + kg * 8;
  const unsigned short* pbl = Wl + (size_t)(n0 + r16) * D + kg * 8;
  f32x4 a0 = {0.f, 0.f, 0.f, 0.f}, a1 = a0;
#pragma unroll 2
  for (int k = khalf * 384; k < khalf * 384 + 384; k += 32) {
    const bf16x8 ah0 = *reinterpret_cast<const bf16x8*>(pah + k);
    const bf16x8 ah1 = *reinterpret_cast<const bf16x8*>(pah + 16 * D + k);
    const bf16x8 al0 = *reinterpret_cast<const bf16x8*>(pal + k);
    const bf16x8 al1 = *reinterpret_cast<const bf16x8*>(pal + 16 * D + k);
    const bf16x8 bh0 = *reinterpret_cast<const bf16x8*>(pbh + k);
    const bf16x8 bl0 = *reinterpret_cast<const bf16x8*>(pbl + k);
    a0 = __builtin_amdgcn_mfma_f32_16x16x32_bf16(ah0, bh0, a0, 0, 0, 0);
    a0 = __builtin_amdgcn_mfma_f32_16x16x32_bf16(ah0, bl0, a0, 0, 0, 0);
    a0 = __builtin_amdgcn_mfma_f32_16x16x32_bf16(al0, bh0, a0, 0, 0, 0);
    a1 = __builtin_amdgcn_mfma_f32_16x16x32_bf16(ah1, bh0, a1, 0, 0, 0);
    a1 = __builtin_amdgcn_mfma_f32_16x16x32_bf16(ah1, bl0, a1, 0, 0, 0);
    a1 = __builtin_amdgcn_mfma_f32_16x16x32_bf16(al1, bh0, a1, 0, 0, 0);
  }
  if (khalf == 1) {
#pragma unroll
    for (int r = 0; r < 4; ++r) {
      CB[pair][lane][r] = a0[r];
      CB[pair][lane][4 + r] = a1[r];
    }
  }
  __syncthreads();
  if (khalf == 1) return;
#pragma unroll
  for (int r = 0; r < 4; ++r) {
    a0[r] += CB[pair][lane][r];
    a1[r] += CB[pair][lane][4 + r];
  }
#pragma unroll
  for (int r = 0; r < 4; ++r) {
    out[(size_t)(m0 + kg * 4 + r) * D + n0 + r16] = a0[r];
    out[(size_t)(m0 + 16 + kg * 4 + r) * D + n0 + r16] = a1[r];
  }
}

extern "C" void kernel_launch(void* const* d_in, const int* in_sizes, int n_in,
                              void* d_out, int out_size, void* d_ws, size_t ws_size,
                              hipStream_t stream) {
  const float* s    = (const float*)d_in[0];
  const float* z    = (const float*)d_in[1];
  const float* Wq   = (const float*)d_in[2];
  const float* bq   = (const float*)d_in[3];
  const float* Wk   = (const float*)d_in[4];
  const float* Wv   = (const float*)d_in[5];
  const float* Wg   = (const float*)d_in[6];
  const float* ln_w = (const float*)d_in[7];
  const float* ln_b = (const float*)d_in[8];
  const float* Wz   = (const float*)d_in[9];
  const float* Wo   = (const float*)d_in[10];
  float* out = (float*)d_out;

  float* g_ws    = (float*)d_ws;                                  // S*D f32
  float* bias_ws = g_ws + (size_t)S * D;                          // H*S*S f32
  unsigned short* wzwb_ws = (unsigned short*)(bias_ws + (size_t)H * S * S);  // 2048 u16
  float* s12_ws  = bias_ws + (size_t)H * S * S + 1024;            // 32 f32
  unsigned short* s_hi = (unsigned short*)(s12_ws + 32);
  unsigned short* s_lo = s_hi + (size_t)S * D;
  unsigned short* w_hi = s_lo + (size_t)S * D;
  unsigned short* w_lo = w_hi + (size_t)5 * D * D;
  unsigned short* a_hi = w_lo + (size_t)5 * D * D;
  unsigned short* a_lo = a_hi + (size_t)S * D;
  unsigned short* q_hi = a_lo + (size_t)S * D;                    // [S][1024] padded
  unsigned short* q_lo = q_hi + (size_t)S * 1024;
  unsigned short* k_hi = q_lo + (size_t)S * 1024;
  unsigned short* k_lo = k_hi + (size_t)S * 1024;
  unsigned short* vt_hi = k_lo + (size_t)S * 1024;                // [768][1024]
  unsigned short* vt_lo = vt_hi + (size_t)D * 1024;

  // A) splits + pb_prep + padzero
  prep_kernel<<<dim3(812, 6), 256, 0, stream>>>(s, Wq, Wk, Wv, Wg, Wo,
                                                s_hi, s_lo, w_hi, w_lo,
                                                Wz, ln_w, ln_b, wzwb_ws, s12_ws,
                                                q_hi, q_lo, k_hi, k_lo);
  // B) qkvg (split-K x2) + pair_bias
  qkvg_mfma_kernel<<<1536, 256, 0, stream>>>(s_hi, s_lo, w_hi, w_lo, bq,
                                             q_hi, q_lo, k_hi, k_lo, vt_hi, vt_lo, g_ws);
  pair_bias_kernel<<<4096, 256, 0, stream>>>(z, wzwb_ws, s12_ws, bias_ws);
  // C) fused KV-split attention (intra-block reduce + gate)
  attn_kernel<<<1024, 256, 0, stream>>>(q_hi, q_lo, k_hi, k_lo,
                                        vt_hi, vt_lo, bias_ws, g_ws, a_hi, a_lo);
  // D) output projection (split-K x2)
  outproj_mfma_kernel<<<768, 256, 0, stream>>>(a_hi, a_lo, w_hi, w_lo, out);
}

// Round 21
// 253.461 us; speedup vs baseline: 1.2212x; 1.2212x over previous
//
#include <hip/hip_runtime.h>

constexpr int H  = 16;
constexpr int HD = 48;
constexpr int D  = 768;    // H*HD
constexpr int DZ = 128;
constexpr int S  = 1024;
constexpr float EPS = 1e-5f;

typedef __attribute__((ext_vector_type(8))) short bf16x8;
typedef __attribute__((ext_vector_type(4))) float f32x4;

__device__ __forceinline__ float sigmoidf_(float x) { return 1.f / (1.f + __expf(-x)); }

__device__ __forceinline__ unsigned short f2b(float f) {
  unsigned u = __float_as_uint(f);
  u += 0x7FFFu + ((u >> 16) & 1u);
  return (unsigned short)(u >> 16);
}
__device__ __forceinline__ void split2(float x, unsigned short& h, unsigned short& l) {
  const unsigned short hb = f2b(x);
  const float hf = __uint_as_float((unsigned)hb << 16);
  h = hb;
  l = f2b(x - hf);
}
__device__ __forceinline__ unsigned pack2(unsigned short a, unsigned short b) {
  return (unsigned)a | ((unsigned)b << 16);
}

// ===========================================================================
// prep v2 (precision-budgeted): s and Wq/Wk/Wv/Wg -> bf16 HI ONLY (plain
// bf16 GEMM path); Wo -> hi+lo (outproj stays split: last stage, errors
// don't attenuate). pb_prep at block 768,y0; padzero (q_hi/k_hi only) at
// blocks 769+. grid dim3(812, 6).
// ===========================================================================
__global__ __launch_bounds__(256)
void prep_kernel(const float* __restrict__ s, const float* __restrict__ Wq,
                 const float* __restrict__ Wk, const float* __restrict__ Wv,
                 const float* __restrict__ Wg, const float* __restrict__ Wo,
                 unsigned short* __restrict__ s_hi,
                 unsigned short* __restrict__ w_hi, unsigned short* __restrict__ w_lo,
                 const float* __restrict__ Wz, const float* __restrict__ ln_w,
                 const float* __restrict__ ln_b, unsigned short* __restrict__ wzwb,
                 float* __restrict__ s12,
                 unsigned short* __restrict__ q_hi, unsigned short* __restrict__ k_hi) {
  if (blockIdx.x >= 769) {
    const int pid = (blockIdx.x - 769) * 6 + blockIdx.y;
    if (pid < 256) {
      const int i = pid * 256 + threadIdx.x;     // < 65536
      const int row = i >> 6, rem = i & 63;
      const int h = rem >> 2, off = (rem & 3) << 2;
      const size_t a = (size_t)row * 1024 + h * 64 + 48 + off;
      const ushort4 zz = {0, 0, 0, 0};
      *reinterpret_cast<ushort4*>(q_hi + a) = zz;
      *reinterpret_cast<ushort4*>(k_hi + a) = zz;
    }
    return;
  }
  if (blockIdx.x == 768) {
    if (blockIdx.y != 0) return;
    const int t = threadIdx.x;
    for (int e = t; e < 16 * DZ; e += 256) wzwb[e] = f2b(Wz[e] * ln_w[e & 127]);
    __syncthreads();
    if (t < 32) {
      const int h = t & 15;
      float a = 0.f;
      if (t < 16) {
        for (int c = 0; c < DZ; ++c) {
          const unsigned u = (unsigned)wzwb[h * DZ + c] << 16;
          a += __uint_as_float(u);
        }
      } else {
        for (int c = 0; c < DZ; ++c) a += Wz[h * DZ + c] * ln_b[c];
      }
      s12[t] = a;
    }
    return;
  }
  const int seg = blockIdx.y;
  const float* src;
  unsigned short* dh;
  unsigned short* dl = nullptr;
  int n;
  if (seg == 0) { src = s; dh = s_hi; n = S * D; }
  else {
    src = (seg == 1) ? Wq : (seg == 2) ? Wk : (seg == 3) ? Wv : (seg == 4) ? Wg : Wo;
    dh = w_hi + (size_t)(seg - 1) * D * D;
    if (seg == 5) dl = w_lo;     // only Wo keeps a lo plane
    n = D * D;
  }
  const int i4 = blockIdx.x * 256 + threadIdx.x;
  if (i4 * 4 < n) {
    const float4 v = *reinterpret_cast<const float4*>(src + (size_t)i4 * 4);
    ushort4 hh, ll;
    split2(v.x, hh.x, ll.x); split2(v.y, hh.y, ll.y);
    split2(v.z, hh.z, ll.z); split2(v.w, hh.w, ll.w);
    *reinterpret_cast<ushort4*>(dh + (size_t)i4 * 4) = hh;
    if (dl) *reinterpret_cast<ushort4*>(dl + (size_t)i4 * 4) = ll;
  }
}

// ---------------------------------------------------------------------------
// Plain-bf16 MFMA GEMM core over K range (32x32 tile/wave): 4 loads + 4 MFMA
// per K=32 step (was 8 + 12 in the split version).
// ---------------------------------------------------------------------------
__device__ __forceinline__ void mfma_core32_bf(const unsigned short* __restrict__ Ah,
                                               const unsigned short* __restrict__ Wh,
                                               const int m0, const int n0,
                                               const int k0, const int k1,
                                               f32x4& a00, f32x4& a01, f32x4& a10, f32x4& a11) {
  const int lane = threadIdx.x & 63;
  const int r16 = lane & 15, kg = lane >> 4;
  const unsigned short* pah = Ah + (size_t)(m0 + r16) * D + kg * 8;
  const unsigned short* pbh = Wh + (size_t)(n0 + r16) * D + kg * 8;
#pragma unroll 2
  for (int k = k0; k < k1; k += 32) {
    const bf16x8 ah0 = *reinterpret_cast<const bf16x8*>(pah + k);
    const bf16x8 ah1 = *reinterpret_cast<const bf16x8*>(pah + 16 * D + k);
    const bf16x8 bh0 = *reinterpret_cast<const bf16x8*>(pbh + k);
    const bf16x8 bh1 = *reinterpret_cast<const bf16x8*>(pbh + 16 * D + k);
    a00 = __builtin_amdgcn_mfma_f32_16x16x32_bf16(ah0, bh0, a00, 0, 0, 0);
    a01 = __builtin_amdgcn_mfma_f32_16x16x32_bf16(ah0, bh1, a01, 0, 0, 0);
    a10 = __builtin_amdgcn_mfma_f32_16x16x32_bf16(ah1, bh0, a10, 0, 0, 0);
    a11 = __builtin_amdgcn_mfma_f32_16x16x32_bf16(ah1, bh1, a11, 0, 0, 0);
  }
}

// ===========================================================================
// qkvg v4: plain-bf16 core (s_hi x w_hi). Outputs: q_hi/k_hi only (hi plane;
// attn QK^T runs hi-only), vt split from the f32 acc (PV keeps 3-term for
// the direct output path), g f32. Split-K x2 structure retained.
// ===========================================================================
__global__ __launch_bounds__(256)
void qkvg_mfma_kernel(const unsigned short* __restrict__ s_hi,
                      const unsigned short* __restrict__ w_hi,
                      const float* __restrict__ bq,
                      unsigned short* __restrict__ q_hi,
                      unsigned short* __restrict__ k_hi,
                      unsigned short* __restrict__ vt_hi, unsigned short* __restrict__ vt_lo,
                      float* __restrict__ g_ws) {
  __shared__ float TT[4][32 * 33];
  __shared__ float CB[2][64][17];
  const int wv = threadIdx.x >> 6;
  const int pair = wv >> 1;
  const int khalf = wv & 1;
  const int tileid = blockIdx.x * 2 + pair;   // 0..3071
  const int wsel = tileid / 768;
  const int rr = tileid % 768;
  const int m0 = (rr / 24) * 32, n0 = (rr % 24) * 32;
  f32x4 a00 = {0.f, 0.f, 0.f, 0.f}, a01 = a00, a10 = a00, a11 = a00;
  mfma_core32_bf(s_hi, w_hi + (size_t)wsel * D * D,
                 m0, n0, khalf * 384, khalf * 384 + 384, a00, a01, a10, a11);
  const int lane = threadIdx.x & 63;
  const int r16 = lane & 15, kg = lane >> 4;
  const float scale = 0.14433756729740643f;  // 1/sqrt(48)

  if (khalf == 1) {
#pragma unroll
    for (int r = 0; r < 4; ++r) {
      CB[pair][lane][r] = a00[r];
      CB[pair][lane][4 + r] = a01[r];
      CB[pair][lane][8 + r] = a10[r];
      CB[pair][lane][12 + r] = a11[r];
    }
  }
  __syncthreads();
  if (khalf == 1) return;
#pragma unroll
  for (int r = 0; r < 4; ++r) {
    a00[r] += CB[pair][lane][r];
    a01[r] += CB[pair][lane][4 + r];
    a10[r] += CB[pair][lane][8 + r];
    a11[r] += CB[pair][lane][12 + r];
  }

  float* T = TT[wv];
#pragma unroll
  for (int r = 0; r < 4; ++r) {
    T[(kg * 4 + r) * 33 + r16] = a00[r];
    T[(kg * 4 + r) * 33 + 16 + r16] = a01[r];
    T[(16 + kg * 4 + r) * 33 + r16] = a10[r];
    T[(16 + kg * 4 + r) * 33 + 16 + r16] = a11[r];
  }
  const int rr2 = lane >> 1, run = lane & 1;
  if (wsel <= 1) {
    const int row = m0 + rr2;
    const int col0 = n0 + run * 16;
    const int hcol0 = (col0 / 48) * 64 + (col0 % 48);
    unsigned short* dh = (wsel == 0) ? q_hi : k_hi;
#pragma unroll
    for (int p4 = 0; p4 < 4; ++p4) {
      float v0 = T[rr2 * 33 + run * 16 + p4 * 4 + 0];
      float v1 = T[rr2 * 33 + run * 16 + p4 * 4 + 1];
      float v2 = T[rr2 * 33 + run * 16 + p4 * 4 + 2];
      float v3 = T[rr2 * 33 + run * 16 + p4 * 4 + 3];
      if (wsel == 0) {
        v0 = (v0 + bq[col0 + p4 * 4 + 0]) * scale;
        v1 = (v1 + bq[col0 + p4 * 4 + 1]) * scale;
        v2 = (v2 + bq[col0 + p4 * 4 + 2]) * scale;
        v3 = (v3 + bq[col0 + p4 * 4 + 3]) * scale;
      }
      uint2 uh;
      uh.x = pack2(f2b(v0), f2b(v1)); uh.y = pack2(f2b(v2), f2b(v3));
      *reinterpret_cast<uint2*>(dh + (size_t)row * 1024 + hcol0 + p4 * 4) = uh;
    }
  } else if (wsel == 2) {
    const int c = lane >> 1;
    const int run2 = lane & 1;
    const int vc = n0 + c;
#pragma unroll
    for (int p4 = 0; p4 < 4; ++p4) {
      unsigned short h0, l0, h1, l1, h2, l2, h3, l3;
      split2(T[(run2 * 16 + p4 * 4 + 0) * 33 + c], h0, l0);
      split2(T[(run2 * 16 + p4 * 4 + 1) * 33 + c], h1, l1);
      split2(T[(run2 * 16 + p4 * 4 + 2) * 33 + c], h2, l2);
      split2(T[(run2 * 16 + p4 * 4 + 3) * 33 + c], h3, l3);
      uint2 uh, ul;
      uh.x = pack2(h0, h1); uh.y = pack2(h2, h3);
      ul.x = pack2(l0, l1); ul.y = pack2(l2, l3);
      *reinterpret_cast<uint2*>(vt_hi + (size_t)vc * 1024 + m0 + run2 * 16 + p4 * 4) = uh;
      *reinterpret_cast<uint2*>(vt_lo + (size_t)vc * 1024 + m0 + run2 * 16 + p4 * 4) = ul;
    }
  } else {
    const int row = m0 + rr2;
#pragma unroll
    for (int p4 = 0; p4 < 4; ++p4) {
      float4 v4;
      v4.x = T[rr2 * 33 + run * 16 + p4 * 4 + 0];
      v4.y = T[rr2 * 33 + run * 16 + p4 * 4 + 1];
      v4.z = T[rr2 * 33 + run * 16 + p4 * 4 + 2];
      v4.w = T[rr2 * 33 + run * 16 + p4 * 4 + 3];
      *reinterpret_cast<float4*>(g_ws + (size_t)row * D + n0 + run * 16 + p4 * 4) = v4;
    }
  }
}

// ---------------------------------------------------------------------------
// pair_bias (unchanged): MFMA z@WzW^T with LN folded into epilogue.
// ---------------------------------------------------------------------------
__global__ __launch_bounds__(256)
void pair_bias_kernel(const float* __restrict__ z, const unsigned short* __restrict__ wzwb,
                      const float* __restrict__ s12, float* __restrict__ bias_out) {
  __shared__ float T[4][64 * 17];
  const int tid = threadIdx.x;
  const int lane = tid & 63;
  const int wv = tid >> 6;
  const int hq = lane & 15;
  const int grp = lane >> 4;

  bf16x8 bf[4];
#pragma unroll
  for (int m = 0; m < 4; ++m)
    bf[m] = *reinterpret_cast<const bf16x8*>(wzwb + hq * DZ + m * 32 + grp * 8);
  const float S1h = s12[hq], S2h = s12[16 + hq];

  const int chunk = blockIdx.x * 4 + wv;
  const size_t p0 = (size_t)chunk * 64;
  float* Tw = &T[wv][0];

#pragma unroll 1
  for (int sub = 0; sub < 4; ++sub) {
    const float* zr = z + (p0 + sub * 16 + hq) * DZ + grp * 8;
    f32x4 acc = {0.f, 0.f, 0.f, 0.f};
    float s1 = 0.f, s2 = 0.f;
#pragma unroll
    for (int m = 0; m < 4; ++m) {
      const float4 a0 = *reinterpret_cast<const float4*>(zr + m * 32);
      const float4 a1 = *reinterpret_cast<const float4*>(zr + m * 32 + 4);
      s1 += (a0.x + a0.y) + (a0.z + a0.w) + (a1.x + a1.y) + (a1.z + a1.w);
      s2 = fmaf(a0.x, a0.x, fmaf(a0.y, a0.y, fmaf(a0.z, a0.z, fmaf(a0.w, a0.w, s2))));
      s2 = fmaf(a1.x, a1.x, fmaf(a1.y, a1.y, fmaf(a1.z, a1.z, fmaf(a1.w, a1.w, s2))));
      bf16x8 af;
      af[0] = (short)f2b(a0.x); af[1] = (short)f2b(a0.y);
      af[2] = (short)f2b(a0.z); af[3] = (short)f2b(a0.w);
      af[4] = (short)f2b(a1.x); af[5] = (short)f2b(a1.y);
      af[6] = (short)f2b(a1.z); af[7] = (short)f2b(a1.w);
      acc = __builtin_amdgcn_mfma_f32_16x16x32_bf16(af, bf[m], acc, 0, 0, 0);
    }
    s1 += __shfl_xor(s1, 16); s1 += __shfl_xor(s1, 32);
    s2 += __shfl_xor(s2, 16); s2 += __shfl_xor(s2, 32);
    const float mu = s1 * (1.f / DZ);
    const float inv = rsqrtf(s2 * (1.f / DZ) - mu * mu + EPS);
#pragma unroll
    for (int r = 0; r < 4; ++r) {
      const int st = grp * 4 + r;
      const float mur = __shfl(mu, st);
      const float invr = __shfl(inv, st);
      Tw[(sub * 16 + st) * 17 + hq] = invr * (acc[r] - mur * S1h) + S2h;
    }
  }
#pragma unroll
  for (int hh = 0; hh < 16; ++hh)
    bias_out[(size_t)hh * S * S + p0 + lane] = Tw[lane * 17 + hh];
}

// ===========================================================================
// Attention v5: QK^T hi-only (2 MFMAs per ts; K traffic halved), PV keeps
// the 3-term split (V is the direct output path). Intra-block KV-split with
// fused reduce (round-19 structure).
// ===========================================================================
constexpr int PST = 72;   // P slab stride (u16)
constexpr int PRS = 52;   // partial-result row stride (f32)

__global__ __launch_bounds__(256)
void attn_kernel(const unsigned short* __restrict__ q_hi,
                 const unsigned short* __restrict__ k_hi,
                 const unsigned short* __restrict__ vt_hi, const unsigned short* __restrict__ vt_lo,
                 const float* __restrict__ bias, const float* __restrict__ g,
                 unsigned short* __restrict__ a_hi, unsigned short* __restrict__ a_lo) {
  __shared__ unsigned short Ph[4][16 * PST], Pl[4][16 * PST];
  __shared__ float Pr[4][16 * PRS];
  const int lane = threadIdx.x & 63;
  const int wv = threadIdx.x >> 6;
  const int h = blockIdx.x >> 6;
  const int qb = blockIdx.x & 63;
  const int q0 = qb << 4;
  const int n16 = lane & 15, kg = lane >> 4;

  const size_t qbase = (size_t)(q0 + n16) * 1024 + h * 64;
  const bf16x8 qh0 = *reinterpret_cast<const bf16x8*>(q_hi + qbase + kg * 8);
  const bf16x8 qh1 = *reinterpret_cast<const bf16x8*>(q_hi + qbase + 32 + kg * 8);

  float mrow = -1e30f, lrow = 0.f;
  f32x4 accO[3] = {};
  unsigned short* php = Ph[wv];
  unsigned short* plp = Pl[wv];

#pragma unroll 1
  for (int t0 = wv * 256; t0 < wv * 256 + 256; t0 += 64) {
    f32x4 sc[4];
#pragma unroll
    for (int ts = 0; ts < 4; ++ts) {
      const size_t kb = (size_t)(t0 + ts * 16 + n16) * 1024 + h * 64;
      const bf16x8 kh0 = *reinterpret_cast<const bf16x8*>(k_hi + kb + kg * 8);
      const bf16x8 kh1 = *reinterpret_cast<const bf16x8*>(k_hi + kb + 32 + kg * 8);
      f32x4 a = *reinterpret_cast<const f32x4*>(
          bias + ((size_t)h * S + (q0 + n16)) * S + t0 + ts * 16 + kg * 4);
      a = __builtin_amdgcn_mfma_f32_16x16x32_bf16(kh0, qh0, a, 0, 0, 0);
      a = __builtin_amdgcn_mfma_f32_16x16x32_bf16(kh1, qh1, a, 0, 0, 0);
      sc[ts] = a;
    }

    float tmax = sc[0][0];
#pragma unroll
    for (int ts = 0; ts < 4; ++ts)
#pragma unroll
      for (int r = 0; r < 4; ++r) tmax = fmaxf(tmax, sc[ts][r]);
    tmax = fmaxf(tmax, __shfl_xor(tmax, 16));
    tmax = fmaxf(tmax, __shfl_xor(tmax, 32));
    const float mn = fmaxf(mrow, tmax);
    const float fac = __expf(mrow - mn);
    mrow = mn;
    float psum = 0.f;
#pragma unroll
    for (int ts = 0; ts < 4; ++ts) {
      const float p0_ = __expf(sc[ts][0] - mn), p1_ = __expf(sc[ts][1] - mn);
      const float p2_ = __expf(sc[ts][2] - mn), p3_ = __expf(sc[ts][3] - mn);
      psum += (p0_ + p1_) + (p2_ + p3_);
      unsigned short h0, l0, h1, l1, h2, l2, h3, l3;
      split2(p0_, h0, l0); split2(p1_, h1, l1); split2(p2_, h2, l2); split2(p3_, h3, l3);
      const int ti = ts * 16 + kg * 4;
      unsigned* wh = reinterpret_cast<unsigned*>(&php[n16 * PST + ti]);
      unsigned* wl = reinterpret_cast<unsigned*>(&plp[n16 * PST + ti]);
      wh[0] = pack2(h0, h1); wh[1] = pack2(h2, h3);
      wl[0] = pack2(l0, l1); wl[1] = pack2(l2, l3);
    }
    lrow = lrow * fac + psum;

    float facr[4];
#pragma unroll
    for (int r = 0; r < 4; ++r) facr[r] = __shfl(fac, kg * 4 + r);
#pragma unroll
    for (int ds = 0; ds < 3; ++ds)
#pragma unroll
      for (int r = 0; r < 4; ++r) accO[ds][r] *= facr[r];

#pragma unroll
    for (int c = 0; c < 2; ++c) {
      const bf16x8 pah = *reinterpret_cast<const bf16x8*>(&php[n16 * PST + c * 32 + kg * 8]);
      const bf16x8 pal = *reinterpret_cast<const bf16x8*>(&plp[n16 * PST + c * 32 + kg * 8]);
#pragma unroll
      for (int ds = 0; ds < 3; ++ds) {
        const size_t vb = (size_t)(h * 48 + ds * 16 + n16) * 1024 + t0 + c * 32 + kg * 8;
        const bf16x8 vh = *reinterpret_cast<const bf16x8*>(vt_hi + vb);
        const bf16x8 vl = *reinterpret_cast<const bf16x8*>(vt_lo + vb);
        accO[ds] = __builtin_amdgcn_mfma_f32_16x16x32_bf16(pah, vh, accO[ds], 0, 0, 0);
        accO[ds] = __builtin_amdgcn_mfma_f32_16x16x32_bf16(pah, vl, accO[ds], 0, 0, 0);
        accO[ds] = __builtin_amdgcn_mfma_f32_16x16x32_bf16(pal, vh, accO[ds], 0, 0, 0);
      }
    }
  }

  lrow += __shfl_xor(lrow, 16);
  lrow += __shfl_xor(lrow, 32);

  float* pw = Pr[wv];
#pragma unroll
  for (int ds = 0; ds < 3; ++ds)
#pragma unroll
    for (int r = 0; r < 4; ++r)
      pw[(kg * 4 + r) * PRS + ds * 16 + n16] = accO[ds][r];
  if (kg == 0) {
    pw[n16 * PRS + 48] = mrow;
    pw[n16 * PRS + 49] = lrow;
  }
  __syncthreads();

  const int row = threadIdx.x >> 4;
  const int dsub = threadIdx.x & 15;
  const float m0_ = Pr[0][row * PRS + 48], m1_ = Pr[1][row * PRS + 48];
  const float m2_ = Pr[2][row * PRS + 48], m3_ = Pr[3][row * PRS + 48];
  const float l0_ = Pr[0][row * PRS + 49], l1_ = Pr[1][row * PRS + 49];
  const float l2_ = Pr[2][row * PRS + 49], l3_ = Pr[3][row * PRS + 49];
  const float M = fmaxf(fmaxf(m0_, m1_), fmaxf(m2_, m3_));
  const float e0 = __expf(m0_ - M), e1 = __expf(m1_ - M);
  const float e2 = __expf(m2_ - M), e3 = __expf(m3_ - M);
  const float rl = 1.f / (l0_ * e0 + l1_ * e1 + l2_ * e2 + l3_ * e3);
#pragma unroll
  for (int j = 0; j < 3; ++j) {
    const int d = dsub * 3 + j;
    const float o = (Pr[0][row * PRS + d] * e0 + Pr[1][row * PRS + d] * e1 +
                     Pr[2][row * PRS + d] * e2 + Pr[3][row * PRS + d] * e3) * rl;
    const size_t idx = (size_t)(q0 + row) * D + h * 48 + d;
    const float a = o * sigmoidf_(g[idx]);
    unsigned short hh, ll;
    split2(a, hh, ll);
    a_hi[idx] = hh;
    a_lo[idx] = ll;
  }
}

// ===========================================================================
// outproj (unchanged, fully split: a hi/lo x Wo hi/lo, split-K x2).
// ===========================================================================
__global__ __launch_bounds__(256)
void outproj_mfma_kernel(const unsigned short* __restrict__ a_hi,
                         const unsigned short* __restrict__ a_lo,
                         const unsigned short* __restrict__ wo_hi,
                         const unsigned short* __restrict__ wo_lo,
                         float* __restrict__ out) {
  __shared__ float CB[2][64][9];
  const int wv = threadIdx.x >> 6;
  const int pair = wv >> 1;
  const int khalf = wv & 1;
  const int tileid = blockIdx.x * 2 + pair;   // 0..1535
  const int m0 = (tileid / 48) * 32, n0 = (tileid % 48) * 16;
  const int lane = threadIdx.x & 63;
  const int r16 = lane & 15, kg = lane >> 4;
  const unsigned short* pah = a_hi + (size_t)(m0 + r16) * D + kg * 8;
  const unsigned short* pal = a_lo + (size_t)(m0 + r16) * D + kg * 8;
  const unsigned short* pbh = wo_hi + (size_t)(n0 + r16) * D + kg * 8;
  const unsigned short* pbl = wo_lo + (size_t)(n0 + r16) * D + kg * 8;
  f32x4 a0 = {0.f, 0.f, 0.f, 0.f}, a1 = a0;
#pragma unroll 2
  for (int k = khalf * 384; k < khalf * 384 + 384; k += 32) {
    const bf16x8 ah0 = *reinterpret_cast<const bf16x8*>(pah + k);
    const bf16x8 ah1 = *reinterpret_cast<const bf16x8*>(pah + 16 * D + k);
    const bf16x8 al0 = *reinterpret_cast<const bf16x8*>(pal + k);
    const bf16x8 al1 = *reinterpret_cast<const bf16x8*>(pal + 16 * D + k);
    const bf16x8 bh0 = *reinterpret_cast<const bf16x8*>(pbh + k);
    const bf16x8 bl0 = *reinterpret_cast<const bf16x8*>(pbl + k);
    a0 = __builtin_amdgcn_mfma_f32_16x16x32_bf16(ah0, bh0, a0, 0, 0, 0);
    a0 = __builtin_amdgcn_mfma_f32_16x16x32_bf16(ah0, bl0, a0, 0, 0, 0);
    a0 = __builtin_amdgcn_mfma_f32_16x16x32_bf16(al0, bh0, a0, 0, 0, 0);
    a1 = __builtin_amdgcn_mfma_f32_16x16x32_bf16(ah1, bh0, a1, 0, 0, 0);
    a1 = __builtin_amdgcn_mfma_f32_16x16x32_bf16(ah1, bl0, a1, 0, 0, 0);
    a1 = __builtin_amdgcn_mfma_f32_16x16x32_bf16(al1, bh0, a1, 0, 0, 0);
  }
  if (khalf == 1) {
#pragma unroll
    for (int r = 0; r < 4; ++r) {
      CB[pair][lane][r] = a0[r];
      CB[pair][lane][4 + r] = a1[r];
    }
  }
  __syncthreads();
  if (khalf == 1) return;
#pragma unroll
  for (int r = 0; r < 4; ++r) {
    a0[r] += CB[pair][lane][r];
    a1[r] += CB[pair][lane][4 + r];
  }
#pragma unroll
  for (int r = 0; r < 4; ++r) {
    out[(size_t)(m0 + kg * 4 + r) * D + n0 + r16] = a0[r];
    out[(size_t)(m0 + 16 + kg * 4 + r) * D + n0 + r16] = a1[r];
  }
}

extern "C" void kernel_launch(void* const* d_in, const int* in_sizes, int n_in,
                              void* d_out, int out_size, void* d_ws, size_t ws_size,
                              hipStream_t stream) {
  const float* s    = (const float*)d_in[0];
  const float* z    = (const float*)d_in[1];
  const float* Wq   = (const float*)d_in[2];
  const float* bq   = (const float*)d_in[3];
  const float* Wk   = (const float*)d_in[4];
  const float* Wv   = (const float*)d_in[5];
  const float* Wg   = (const float*)d_in[6];
  const float* ln_w = (const float*)d_in[7];
  const float* ln_b = (const float*)d_in[8];
  const float* Wz   = (const float*)d_in[9];
  const float* Wo   = (const float*)d_in[10];
  float* out = (float*)d_out;

  float* g_ws    = (float*)d_ws;                                  // S*D f32
  float* bias_ws = g_ws + (size_t)S * D;                          // H*S*S f32
  unsigned short* wzwb_ws = (unsigned short*)(bias_ws + (size_t)H * S * S);  // 2048 u16
  float* s12_ws  = bias_ws + (size_t)H * S * S + 1024;            // 32 f32
  unsigned short* s_hi = (unsigned short*)(s12_ws + 32);          // S*D
  unsigned short* w_hi = s_hi + (size_t)S * D;                    // 5*D*D
  unsigned short* wo_lo = w_hi + (size_t)5 * D * D;               // D*D (Wo lo)
  unsigned short* a_hi = wo_lo + (size_t)D * D;                   // S*D
  unsigned short* a_lo = a_hi + (size_t)S * D;                    // S*D
  unsigned short* q_hi = a_lo + (size_t)S * D;                    // [S][1024] padded
  unsigned short* k_hi = q_hi + (size_t)S * 1024;
  unsigned short* vt_hi = k_hi + (size_t)S * 1024;                // [768][1024]
  unsigned short* vt_lo = vt_hi + (size_t)D * 1024;

  // A) splits (hi-only except Wo) + pb_prep + padzero
  prep_kernel<<<dim3(812, 6), 256, 0, stream>>>(s, Wq, Wk, Wv, Wg, Wo,
                                                s_hi, w_hi, wo_lo,
                                                Wz, ln_w, ln_b, wzwb_ws, s12_ws,
                                                q_hi, k_hi);
  // B) qkvg (plain bf16, split-K x2) + pair_bias
  qkvg_mfma_kernel<<<1536, 256, 0, stream>>>(s_hi, w_hi, bq,
                                             q_hi, k_hi, vt_hi, vt_lo, g_ws);
  pair_bias_kernel<<<4096, 256, 0, stream>>>(z, wzwb_ws, s12_ws, bias_ws);
  // C) fused KV-split attention (QK hi-only; PV split; gate fused)
  attn_kernel<<<1024, 256, 0, stream>>>(q_hi, k_hi, vt_hi, vt_lo,
                                        bias_ws, g_ws, a_hi, a_lo);
  // D) output projection (fully split)
  outproj_mfma_kernel<<<768, 256, 0, stream>>>(a_hi, a_lo, w_hi + (size_t)4 * D * D,
                                               wo_lo, out);
}

// Round 22
// 236.358 us; speedup vs baseline: 1.3096x; 1.0724x over previous
//
#include <hip/hip_runtime.h>

constexpr int H  = 16;
constexpr int HD = 48;
constexpr int D  = 768;    // H*HD
constexpr int DZ = 128;
constexpr int S  = 1024;
constexpr float EPS = 1e-5f;

typedef __attribute__((ext_vector_type(8))) short bf16x8;
typedef __attribute__((ext_vector_type(4))) float f32x4;

__device__ __forceinline__ float sigmoidf_(float x) { return 1.f / (1.f + __expf(-x)); }

__device__ __forceinline__ unsigned short f2b(float f) {
  unsigned u = __float_as_uint(f);
  u += 0x7FFFu + ((u >> 16) & 1u);
  return (unsigned short)(u >> 16);
}
__device__ __forceinline__ void split2(float x, unsigned short& h, unsigned short& l) {
  const unsigned short hb = f2b(x);
  const float hf = __uint_as_float((unsigned)hb << 16);
  h = hb;
  l = f2b(x - hf);
}
__device__ __forceinline__ unsigned pack2(unsigned short a, unsigned short b) {
  return (unsigned)a | ((unsigned)b << 16);
}

// ===========================================================================
// prep (round-21 structure): s + Wq/Wk/Wv/Wg -> bf16 hi only; Wo -> hi+lo
// (outproj weight stays split). pb_prep at block 768,y0; padzero 769+.
// ===========================================================================
__global__ __launch_bounds__(256)
void prep_kernel(const float* __restrict__ s, const float* __restrict__ Wq,
                 const float* __restrict__ Wk, const float* __restrict__ Wv,
                 const float* __restrict__ Wg, const float* __restrict__ Wo,
                 unsigned short* __restrict__ s_hi,
                 unsigned short* __restrict__ w_hi, unsigned short* __restrict__ w_lo,
                 const float* __restrict__ Wz, const float* __restrict__ ln_w,
                 const float* __restrict__ ln_b, unsigned short* __restrict__ wzwb,
                 float* __restrict__ s12,
                 unsigned short* __restrict__ q_hi, unsigned short* __restrict__ k_hi) {
  if (blockIdx.x >= 769) {
    const int pid = (blockIdx.x - 769) * 6 + blockIdx.y;
    if (pid < 256) {
      const int i = pid * 256 + threadIdx.x;     // < 65536
      const int row = i >> 6, rem = i & 63;
      const int h = rem >> 2, off = (rem & 3) << 2;
      const size_t a = (size_t)row * 1024 + h * 64 + 48 + off;
      const ushort4 zz = {0, 0, 0, 0};
      *reinterpret_cast<ushort4*>(q_hi + a) = zz;
      *reinterpret_cast<ushort4*>(k_hi + a) = zz;
    }
    return;
  }
  if (blockIdx.x == 768) {
    if (blockIdx.y != 0) return;
    const int t = threadIdx.x;
    for (int e = t; e < 16 * DZ; e += 256) wzwb[e] = f2b(Wz[e] * ln_w[e & 127]);
    __syncthreads();
    if (t < 32) {
      const int h = t & 15;
      float a = 0.f;
      if (t < 16) {
        for (int c = 0; c < DZ; ++c) {
          const unsigned u = (unsigned)wzwb[h * DZ + c] << 16;
          a += __uint_as_float(u);
        }
      } else {
        for (int c = 0; c < DZ; ++c) a += Wz[h * DZ + c] * ln_b[c];
      }
      s12[t] = a;
    }
    return;
  }
  const int seg = blockIdx.y;
  const float* src;
  unsigned short* dh;
  unsigned short* dl = nullptr;
  int n;
  if (seg == 0) { src = s; dh = s_hi; n = S * D; }
  else {
    src = (seg == 1) ? Wq : (seg == 2) ? Wk : (seg == 3) ? Wv : (seg == 4) ? Wg : Wo;
    dh = w_hi + (size_t)(seg - 1) * D * D;
    if (seg == 5) dl = w_lo;     // only Wo keeps a lo plane
    n = D * D;
  }
  const int i4 = blockIdx.x * 256 + threadIdx.x;
  if (i4 * 4 < n) {
    const float4 v = *reinterpret_cast<const float4*>(src + (size_t)i4 * 4);
    ushort4 hh, ll;
    split2(v.x, hh.x, ll.x); split2(v.y, hh.y, ll.y);
    split2(v.z, hh.z, ll.z); split2(v.w, hh.w, ll.w);
    *reinterpret_cast<ushort4*>(dh + (size_t)i4 * 4) = hh;
    if (dl) *reinterpret_cast<ushort4*>(dl + (size_t)i4 * 4) = ll;
  }
}

// ---------------------------------------------------------------------------
// Plain-bf16 MFMA GEMM core over K range (32x32 tile/wave).
// ---------------------------------------------------------------------------
__device__ __forceinline__ void mfma_core32_bf(const unsigned short* __restrict__ Ah,
                                               const unsigned short* __restrict__ Wh,
                                               const int m0, const int n0,
                                               const int k0, const int k1,
                                               f32x4& a00, f32x4& a01, f32x4& a10, f32x4& a11) {
  const int lane = threadIdx.x & 63;
  const int r16 = lane & 15, kg = lane >> 4;
  const unsigned short* pah = Ah + (size_t)(m0 + r16) * D + kg * 8;
  const unsigned short* pbh = Wh + (size_t)(n0 + r16) * D + kg * 8;
#pragma unroll 2
  for (int k = k0; k < k1; k += 32) {
    const bf16x8 ah0 = *reinterpret_cast<const bf16x8*>(pah + k);
    const bf16x8 ah1 = *reinterpret_cast<const bf16x8*>(pah + 16 * D + k);
    const bf16x8 bh0 = *reinterpret_cast<const bf16x8*>(pbh + k);
    const bf16x8 bh1 = *reinterpret_cast<const bf16x8*>(pbh + 16 * D + k);
    a00 = __builtin_amdgcn_mfma_f32_16x16x32_bf16(ah0, bh0, a00, 0, 0, 0);
    a01 = __builtin_amdgcn_mfma_f32_16x16x32_bf16(ah0, bh1, a01, 0, 0, 0);
    a10 = __builtin_amdgcn_mfma_f32_16x16x32_bf16(ah1, bh0, a10, 0, 0, 0);
    a11 = __builtin_amdgcn_mfma_f32_16x16x32_bf16(ah1, bh1, a11, 0, 0, 0);
  }
}

// ===========================================================================
// qkvg v5: plain-bf16 core; outputs q_hi/k_hi, vt_hi ONLY (V hi-only now),
// g f32. Split-K x2 retained.
// ===========================================================================
__global__ __launch_bounds__(256)
void qkvg_mfma_kernel(const unsigned short* __restrict__ s_hi,
                      const unsigned short* __restrict__ w_hi,
                      const float* __restrict__ bq,
                      unsigned short* __restrict__ q_hi,
                      unsigned short* __restrict__ k_hi,
                      unsigned short* __restrict__ vt_hi,
                      float* __restrict__ g_ws) {
  __shared__ float TT[4][32 * 33];
  __shared__ float CB[2][64][17];
  const int wv = threadIdx.x >> 6;
  const int pair = wv >> 1;
  const int khalf = wv & 1;
  const int tileid = blockIdx.x * 2 + pair;   // 0..3071
  const int wsel = tileid / 768;
  const int rr = tileid % 768;
  const int m0 = (rr / 24) * 32, n0 = (rr % 24) * 32;
  f32x4 a00 = {0.f, 0.f, 0.f, 0.f}, a01 = a00, a10 = a00, a11 = a00;
  mfma_core32_bf(s_hi, w_hi + (size_t)wsel * D * D,
                 m0, n0, khalf * 384, khalf * 384 + 384, a00, a01, a10, a11);
  const int lane = threadIdx.x & 63;
  const int r16 = lane & 15, kg = lane >> 4;
  const float scale = 0.14433756729740643f;  // 1/sqrt(48)

  if (khalf == 1) {
#pragma unroll
    for (int r = 0; r < 4; ++r) {
      CB[pair][lane][r] = a00[r];
      CB[pair][lane][4 + r] = a01[r];
      CB[pair][lane][8 + r] = a10[r];
      CB[pair][lane][12 + r] = a11[r];
    }
  }
  __syncthreads();
  if (khalf == 1) return;
#pragma unroll
  for (int r = 0; r < 4; ++r) {
    a00[r] += CB[pair][lane][r];
    a01[r] += CB[pair][lane][4 + r];
    a10[r] += CB[pair][lane][8 + r];
    a11[r] += CB[pair][lane][12 + r];
  }

  float* T = TT[wv];
#pragma unroll
  for (int r = 0; r < 4; ++r) {
    T[(kg * 4 + r) * 33 + r16] = a00[r];
    T[(kg * 4 + r) * 33 + 16 + r16] = a01[r];
    T[(16 + kg * 4 + r) * 33 + r16] = a10[r];
    T[(16 + kg * 4 + r) * 33 + 16 + r16] = a11[r];
  }
  const int rr2 = lane >> 1, run = lane & 1;
  if (wsel <= 1) {
    const int row = m0 + rr2;
    const int col0 = n0 + run * 16;
    const int hcol0 = (col0 / 48) * 64 + (col0 % 48);
    unsigned short* dh = (wsel == 0) ? q_hi : k_hi;
#pragma unroll
    for (int p4 = 0; p4 < 4; ++p4) {
      float v0 = T[rr2 * 33 + run * 16 + p4 * 4 + 0];
      float v1 = T[rr2 * 33 + run * 16 + p4 * 4 + 1];
      float v2 = T[rr2 * 33 + run * 16 + p4 * 4 + 2];
      float v3 = T[rr2 * 33 + run * 16 + p4 * 4 + 3];
      if (wsel == 0) {
        v0 = (v0 + bq[col0 + p4 * 4 + 0]) * scale;
        v1 = (v1 + bq[col0 + p4 * 4 + 1]) * scale;
        v2 = (v2 + bq[col0 + p4 * 4 + 2]) * scale;
        v3 = (v3 + bq[col0 + p4 * 4 + 3]) * scale;
      }
      uint2 uh;
      uh.x = pack2(f2b(v0), f2b(v1)); uh.y = pack2(f2b(v2), f2b(v3));
      *reinterpret_cast<uint2*>(dh + (size_t)row * 1024 + hcol0 + p4 * 4) = uh;
    }
  } else if (wsel == 2) {
    const int c = lane >> 1;
    const int run2 = lane & 1;
    const int vc = n0 + c;
#pragma unroll
    for (int p4 = 0; p4 < 4; ++p4) {
      uint2 uh;
      uh.x = pack2(f2b(T[(run2 * 16 + p4 * 4 + 0) * 33 + c]),
                   f2b(T[(run2 * 16 + p4 * 4 + 1) * 33 + c]));
      uh.y = pack2(f2b(T[(run2 * 16 + p4 * 4 + 2) * 33 + c]),
                   f2b(T[(run2 * 16 + p4 * 4 + 3) * 33 + c]));
      *reinterpret_cast<uint2*>(vt_hi + (size_t)vc * 1024 + m0 + run2 * 16 + p4 * 4) = uh;
    }
  } else {
    const int row = m0 + rr2;
#pragma unroll
    for (int p4 = 0; p4 < 4; ++p4) {
      float4 v4;
      v4.x = T[rr2 * 33 + run * 16 + p4 * 4 + 0];
      v4.y = T[rr2 * 33 + run * 16 + p4 * 4 + 1];
      v4.z = T[rr2 * 33 + run * 16 + p4 * 4 + 2];
      v4.w = T[rr2 * 33 + run * 16 + p4 * 4 + 3];
      *reinterpret_cast<float4*>(g_ws + (size_t)row * D + n0 + run * 16 + p4 * 4) = v4;
    }
  }
}

// ---------------------------------------------------------------------------
// pair_bias (unchanged): MFMA z@WzW^T with LN folded into epilogue.
// ---------------------------------------------------------------------------
__global__ __launch_bounds__(256)
void pair_bias_kernel(const float* __restrict__ z, const unsigned short* __restrict__ wzwb,
                      const float* __restrict__ s12, float* __restrict__ bias_out) {
  __shared__ float T[4][64 * 17];
  const int tid = threadIdx.x;
  const int lane = tid & 63;
  const int wv = tid >> 6;
  const int hq = lane & 15;
  const int grp = lane >> 4;

  bf16x8 bf[4];
#pragma unroll
  for (int m = 0; m < 4; ++m)
    bf[m] = *reinterpret_cast<const bf16x8*>(wzwb + hq * DZ + m * 32 + grp * 8);
  const float S1h = s12[hq], S2h = s12[16 + hq];

  const int chunk = blockIdx.x * 4 + wv;
  const size_t p0 = (size_t)chunk * 64;
  float* Tw = &T[wv][0];

#pragma unroll 1
  for (int sub = 0; sub < 4; ++sub) {
    const float* zr = z + (p0 + sub * 16 + hq) * DZ + grp * 8;
    f32x4 acc = {0.f, 0.f, 0.f, 0.f};
    float s1 = 0.f, s2 = 0.f;
#pragma unroll
    for (int m = 0; m < 4; ++m) {
      const float4 a0 = *reinterpret_cast<const float4*>(zr + m * 32);
      const float4 a1 = *reinterpret_cast<const float4*>(zr + m * 32 + 4);
      s1 += (a0.x + a0.y) + (a0.z + a0.w) + (a1.x + a1.y) + (a1.z + a1.w);
      s2 = fmaf(a0.x, a0.x, fmaf(a0.y, a0.y, fmaf(a0.z, a0.z, fmaf(a0.w, a0.w, s2))));
      s2 = fmaf(a1.x, a1.x, fmaf(a1.y, a1.y, fmaf(a1.z, a1.z, fmaf(a1.w, a1.w, s2))));
      bf16x8 af;
      af[0] = (short)f2b(a0.x); af[1] = (short)f2b(a0.y);
      af[2] = (short)f2b(a0.z); af[3] = (short)f2b(a0.w);
      af[4] = (short)f2b(a1.x); af[5] = (short)f2b(a1.y);
      af[6] = (short)f2b(a1.z); af[7] = (short)f2b(a1.w);
      acc = __builtin_amdgcn_mfma_f32_16x16x32_bf16(af, bf[m], acc, 0, 0, 0);
    }
    s1 += __shfl_xor(s1, 16); s1 += __shfl_xor(s1, 32);
    s2 += __shfl_xor(s2, 16); s2 += __shfl_xor(s2, 32);
    const float mu = s1 * (1.f / DZ);
    const float inv = rsqrtf(s2 * (1.f / DZ) - mu * mu + EPS);
#pragma unroll
    for (int r = 0; r < 4; ++r) {
      const int st = grp * 4 + r;
      const float mur = __shfl(mu, st);
      const float invr = __shfl(inv, st);
      Tw[(sub * 16 + st) * 17 + hq] = invr * (acc[r] - mur * S1h) + S2h;
    }
  }
#pragma unroll
  for (int hh = 0; hh < 16; ++hh)
    bias_out[(size_t)hh * S * S + p0 + lane] = Tw[lane * 17 + hh];
}

// ===========================================================================
// Attention v6: QK^T hi-only; PV = (P_hi + P_lo) x V_hi (2 MFMAs); a_hi-only
// output. Intra-block KV-split with fused reduce (round-19 structure).
// ===========================================================================
constexpr int PST = 72;   // P slab stride (u16)
constexpr int PRS = 52;   // partial-result row stride (f32)

__global__ __launch_bounds__(256)
void attn_kernel(const unsigned short* __restrict__ q_hi,
                 const unsigned short* __restrict__ k_hi,
                 const unsigned short* __restrict__ vt_hi,
                 const float* __restrict__ bias, const float* __restrict__ g,
                 unsigned short* __restrict__ a_hi) {
  __shared__ unsigned short Ph[4][16 * PST], Pl[4][16 * PST];
  __shared__ float Pr[4][16 * PRS];
  const int lane = threadIdx.x & 63;
  const int wv = threadIdx.x >> 6;
  const int h = blockIdx.x >> 6;
  const int qb = blockIdx.x & 63;
  const int q0 = qb << 4;
  const int n16 = lane & 15, kg = lane >> 4;

  const size_t qbase = (size_t)(q0 + n16) * 1024 + h * 64;
  const bf16x8 qh0 = *reinterpret_cast<const bf16x8*>(q_hi + qbase + kg * 8);
  const bf16x8 qh1 = *reinterpret_cast<const bf16x8*>(q_hi + qbase + 32 + kg * 8);

  float mrow = -1e30f, lrow = 0.f;
  f32x4 accO[3] = {};
  unsigned short* php = Ph[wv];
  unsigned short* plp = Pl[wv];

#pragma unroll 1
  for (int t0 = wv * 256; t0 < wv * 256 + 256; t0 += 64) {
    f32x4 sc[4];
#pragma unroll
    for (int ts = 0; ts < 4; ++ts) {
      const size_t kb = (size_t)(t0 + ts * 16 + n16) * 1024 + h * 64;
      const bf16x8 kh0 = *reinterpret_cast<const bf16x8*>(k_hi + kb + kg * 8);
      const bf16x8 kh1 = *reinterpret_cast<const bf16x8*>(k_hi + kb + 32 + kg * 8);
      f32x4 a = *reinterpret_cast<const f32x4*>(
          bias + ((size_t)h * S + (q0 + n16)) * S + t0 + ts * 16 + kg * 4);
      a = __builtin_amdgcn_mfma_f32_16x16x32_bf16(kh0, qh0, a, 0, 0, 0);
      a = __builtin_amdgcn_mfma_f32_16x16x32_bf16(kh1, qh1, a, 0, 0, 0);
      sc[ts] = a;
    }

    float tmax = sc[0][0];
#pragma unroll
    for (int ts = 0; ts < 4; ++ts)
#pragma unroll
      for (int r = 0; r < 4; ++r) tmax = fmaxf(tmax, sc[ts][r]);
    tmax = fmaxf(tmax, __shfl_xor(tmax, 16));
    tmax = fmaxf(tmax, __shfl_xor(tmax, 32));
    const float mn = fmaxf(mrow, tmax);
    const float fac = __expf(mrow - mn);
    mrow = mn;
    float psum = 0.f;
#pragma unroll
    for (int ts = 0; ts < 4; ++ts) {
      const float p0_ = __expf(sc[ts][0] - mn), p1_ = __expf(sc[ts][1] - mn);
      const float p2_ = __expf(sc[ts][2] - mn), p3_ = __expf(sc[ts][3] - mn);
      psum += (p0_ + p1_) + (p2_ + p3_);
      unsigned short h0, l0, h1, l1, h2, l2, h3, l3;
      split2(p0_, h0, l0); split2(p1_, h1, l1); split2(p2_, h2, l2); split2(p3_, h3, l3);
      const int ti = ts * 16 + kg * 4;
      unsigned* wh = reinterpret_cast<unsigned*>(&php[n16 * PST + ti]);
      unsigned* wl = reinterpret_cast<unsigned*>(&plp[n16 * PST + ti]);
      wh[0] = pack2(h0, h1); wh[1] = pack2(h2, h3);
      wl[0] = pack2(l0, l1); wl[1] = pack2(l2, l3);
    }
    lrow = lrow * fac + psum;

    float facr[4];
#pragma unroll
    for (int r = 0; r < 4; ++r) facr[r] = __shfl(fac, kg * 4 + r);
#pragma unroll
    for (int ds = 0; ds < 3; ++ds)
#pragma unroll
      for (int r = 0; r < 4; ++r) accO[ds][r] *= facr[r];

#pragma unroll
    for (int c = 0; c < 2; ++c) {
      const bf16x8 pah = *reinterpret_cast<const bf16x8*>(&php[n16 * PST + c * 32 + kg * 8]);
      const bf16x8 pal = *reinterpret_cast<const bf16x8*>(&plp[n16 * PST + c * 32 + kg * 8]);
#pragma unroll
      for (int ds = 0; ds < 3; ++ds) {
        const size_t vb = (size_t)(h * 48 + ds * 16 + n16) * 1024 + t0 + c * 32 + kg * 8;
        const bf16x8 vh = *reinterpret_cast<const bf16x8*>(vt_hi + vb);
        accO[ds] = __builtin_amdgcn_mfma_f32_16x16x32_bf16(pah, vh, accO[ds], 0, 0, 0);
        accO[ds] = __builtin_amdgcn_mfma_f32_16x16x32_bf16(pal, vh, accO[ds], 0, 0, 0);
      }
    }
  }

  lrow += __shfl_xor(lrow, 16);
  lrow += __shfl_xor(lrow, 32);

  float* pw = Pr[wv];
#pragma unroll
  for (int ds = 0; ds < 3; ++ds)
#pragma unroll
    for (int r = 0; r < 4; ++r)
      pw[(kg * 4 + r) * PRS + ds * 16 + n16] = accO[ds][r];
  if (kg == 0) {
    pw[n16 * PRS + 48] = mrow;
    pw[n16 * PRS + 49] = lrow;
  }
  __syncthreads();

  const int row = threadIdx.x >> 4;
  const int dsub = threadIdx.x & 15;
  const float m0_ = Pr[0][row * PRS + 48], m1_ = Pr[1][row * PRS + 48];
  const float m2_ = Pr[2][row * PRS + 48], m3_ = Pr[3][row * PRS + 48];
  const float l0_ = Pr[0][row * PRS + 49], l1_ = Pr[1][row * PRS + 49];
  const float l2_ = Pr[2][row * PRS + 49], l3_ = Pr[3][row * PRS + 49];
  const float M = fmaxf(fmaxf(m0_, m1_), fmaxf(m2_, m3_));
  const float e0 = __expf(m0_ - M), e1 = __expf(m1_ - M);
  const float e2 = __expf(m2_ - M), e3 = __expf(m3_ - M);
  const float rl = 1.f / (l0_ * e0 + l1_ * e1 + l2_ * e2 + l3_ * e3);
#pragma unroll
  for (int j = 0; j < 3; ++j) {
    const int d = dsub * 3 + j;
    const float o = (Pr[0][row * PRS + d] * e0 + Pr[1][row * PRS + d] * e1 +
                     Pr[2][row * PRS + d] * e2 + Pr[3][row * PRS + d] * e3) * rl;
    const size_t idx = (size_t)(q0 + row) * D + h * 48 + d;
    const float a = o * sigmoidf_(g[idx]);
    a_hi[idx] = f2b(a);
  }
}

// ===========================================================================
// outproj v4: a hi-only x Wo (hi+lo): 4 MFMAs + 4 loads per K=32 step.
// Split-K x2 retained.
// ===========================================================================
__global__ __launch_bounds__(256)
void outproj_mfma_kernel(const unsigned short* __restrict__ a_hi,
                         const unsigned short* __restrict__ wo_hi,
                         const unsigned short* __restrict__ wo_lo,
                         float* __restrict__ out) {
  __shared__ float CB[2][64][9];
  const int wv = threadIdx.x >> 6;
  const int pair = wv >> 1;
  const int khalf = wv & 1;
  const int tileid = blockIdx.x * 2 + pair;   // 0..1535
  const int m0 = (tileid / 48) * 32, n0 = (tileid % 48) * 16;
  const int lane = threadIdx.x & 63;
  const int r16 = lane & 15, kg = lane >> 4;
  const unsigned short* pah = a_hi + (size_t)(m0 + r16) * D + kg * 8;
  const unsigned short* pbh = wo_hi + (size_t)(n0 + r16) * D + kg * 8;
  const unsigned short* pbl = wo_lo + (size_t)(n0 + r16) * D + kg * 8;
  f32x4 a0 = {0.f, 0.f, 0.f, 0.f}, a1 = a0;
#pragma unroll 2
  for (int k = khalf * 384; k < khalf * 384 + 384; k += 32) {
    const bf16x8 ah0 = *reinterpret_cast<const bf16x8*>(pah + k);
    const bf16x8 ah1 = *reinterpret_cast<const bf16x8*>(pah + 16 * D + k);
    const bf16x8 bh0 = *reinterpret_cast<const bf16x8*>(pbh + k);
    const bf16x8 bl0 = *reinterpret_cast<const bf16x8*>(pbl + k);
    a0 = __builtin_amdgcn_mfma_f32_16x16x32_bf16(ah0, bh0, a0, 0, 0, 0);
    a0 = __builtin_amdgcn_mfma_f32_16x16x32_bf16(ah0, bl0, a0, 0, 0, 0);
    a1 = __builtin_amdgcn_mfma_f32_16x16x32_bf16(ah1, bh0, a1, 0, 0, 0);
    a1 = __builtin_amdgcn_mfma_f32_16x16x32_bf16(ah1, bl0, a1, 0, 0, 0);
  }
  if (khalf == 1) {
#pragma unroll
    for (int r = 0; r < 4; ++r) {
      CB[pair][lane][r] = a0[r];
      CB[pair][lane][4 + r] = a1[r];
    }
  }
  __syncthreads();
  if (khalf == 1) return;
#pragma unroll
  for (int r = 0; r < 4; ++r) {
    a0[r] += CB[pair][lane][r];
    a1[r] += CB[pair][lane][4 + r];
  }
#pragma unroll
  for (int r = 0; r < 4; ++r) {
    out[(size_t)(m0 + kg * 4 + r) * D + n0 + r16] = a0[r];
    out[(size_t)(m0 + 16 + kg * 4 + r) * D + n0 + r16] = a1[r];
  }
}

extern "C" void kernel_launch(void* const* d_in, const int* in_sizes, int n_in,
                              void* d_out, int out_size, void* d_ws, size_t ws_size,
                              hipStream_t stream) {
  const float* s    = (const float*)d_in[0];
  const float* z    = (const float*)d_in[1];
  const float* Wq   = (const float*)d_in[2];
  const float* bq   = (const float*)d_in[3];
  const float* Wk   = (const float*)d_in[4];
  const float* Wv   = (const float*)d_in[5];
  const float* Wg   = (const float*)d_in[6];
  const float* ln_w = (const float*)d_in[7];
  const float* ln_b = (const float*)d_in[8];
  const float* Wz   = (const float*)d_in[9];
  const float* Wo   = (const float*)d_in[10];
  float* out = (float*)d_out;

  float* g_ws    = (float*)d_ws;                                  // S*D f32
  float* bias_ws = g_ws + (size_t)S * D;                          // H*S*S f32
  unsigned short* wzwb_ws = (unsigned short*)(bias_ws + (size_t)H * S * S);  // 2048 u16
  float* s12_ws  = bias_ws + (size_t)H * S * S + 1024;            // 32 f32
  unsigned short* s_hi = (unsigned short*)(s12_ws + 32);          // S*D
  unsigned short* w_hi = s_hi + (size_t)S * D;                    // 5*D*D
  unsigned short* wo_lo = w_hi + (size_t)5 * D * D;               // D*D (Wo lo)
  unsigned short* a_hi = wo_lo + (size_t)D * D;                   // S*D
  unsigned short* q_hi = a_hi + (size_t)S * D;                    // [S][1024] padded
  unsigned short* k_hi = q_hi + (size_t)S * 1024;
  unsigned short* vt_hi = k_hi + (size_t)S * 1024;                // [768][1024]

  // A) splits (hi-only except Wo) + pb_prep + padzero
  prep_kernel<<<dim3(812, 6), 256, 0, stream>>>(s, Wq, Wk, Wv, Wg, Wo,
                                                s_hi, w_hi, wo_lo,
                                                Wz, ln_w, ln_b, wzwb_ws, s12_ws,
                                                q_hi, k_hi);
  // B) qkvg (plain bf16, split-K x2) + pair_bias
  qkvg_mfma_kernel<<<1536, 256, 0, stream>>>(s_hi, w_hi, bq,
                                             q_hi, k_hi, vt_hi, g_ws);
  pair_bias_kernel<<<4096, 256, 0, stream>>>(z, wzwb_ws, s12_ws, bias_ws);
  // C) fused KV-split attention (QK hi; PV split-P x V_hi; gate fused)
  attn_kernel<<<1024, 256, 0, stream>>>(q_hi, k_hi, vt_hi,
                                        bias_ws, g_ws, a_hi);
  // D) output projection (a hi x Wo split)
  outproj_mfma_kernel<<<768, 256, 0, stream>>>(a_hi, w_hi + (size_t)4 * D * D,
                                               wo_lo, out);
}

// Round 23
// 221.476 us; speedup vs baseline: 1.3976x; 1.0672x over previous
//
#include <hip/hip_runtime.h>

constexpr int H  = 16;
constexpr int HD = 48;
constexpr int D  = 768;    // H*HD
constexpr int DZ = 128;
constexpr int S  = 1024;
constexpr float EPS = 1e-5f;

typedef __attribute__((ext_vector_type(8))) short bf16x8;
typedef __attribute__((ext_vector_type(4))) float f32x4;

__device__ __forceinline__ float sigmoidf_(float x) { return 1.f / (1.f + __expf(-x)); }

__device__ __forceinline__ unsigned short f2b(float f) {
  unsigned u = __float_as_uint(f);
  u += 0x7FFFu + ((u >> 16) & 1u);
  return (unsigned short)(u >> 16);
}
__device__ __forceinline__ float b2f(unsigned short u) {
  return __uint_as_float((unsigned)u << 16);
}
__device__ __forceinline__ void split2(float x, unsigned short& h, unsigned short& l) {
  const unsigned short hb = f2b(x);
  const float hf = __uint_as_float((unsigned)hb << 16);
  h = hb;
  l = f2b(x - hf);
}
__device__ __forceinline__ unsigned pack2(unsigned short a, unsigned short b) {
  return (unsigned)a | ((unsigned)b << 16);
}

// ===========================================================================
// prep (unchanged structure): s + Wq/Wk/Wv/Wg -> bf16 hi only; Wo -> hi+lo.
// pb_prep at block 768,y0; padzero 769+.
// ===========================================================================
__global__ __launch_bounds__(256)
void prep_kernel(const float* __restrict__ s, const float* __restrict__ Wq,
                 const float* __restrict__ Wk, const float* __restrict__ Wv,
                 const float* __restrict__ Wg, const float* __restrict__ Wo,
                 unsigned short* __restrict__ s_hi,
                 unsigned short* __restrict__ w_hi, unsigned short* __restrict__ w_lo,
                 const float* __restrict__ Wz, const float* __restrict__ ln_w,
                 const float* __restrict__ ln_b, unsigned short* __restrict__ wzwb,
                 float* __restrict__ s12,
                 unsigned short* __restrict__ q_hi, unsigned short* __restrict__ k_hi) {
  if (blockIdx.x >= 769) {
    const int pid = (blockIdx.x - 769) * 6 + blockIdx.y;
    if (pid < 256) {
      const int i = pid * 256 + threadIdx.x;     // < 65536
      const int row = i >> 6, rem = i & 63;
      const int h = rem >> 2, off = (rem & 3) << 2;
      const size_t a = (size_t)row * 1024 + h * 64 + 48 + off;
      const ushort4 zz = {0, 0, 0, 0};
      *reinterpret_cast<ushort4*>(q_hi + a) = zz;
      *reinterpret_cast<ushort4*>(k_hi + a) = zz;
    }
    return;
  }
  if (blockIdx.x == 768) {
    if (blockIdx.y != 0) return;
    const int t = threadIdx.x;
    for (int e = t; e < 16 * DZ; e += 256) wzwb[e] = f2b(Wz[e] * ln_w[e & 127]);
    __syncthreads();
    if (t < 32) {
      const int h = t & 15;
      float a = 0.f;
      if (t < 16) {
        for (int c = 0; c < DZ; ++c) {
          const unsigned u = (unsigned)wzwb[h * DZ + c] << 16;
          a += __uint_as_float(u);
        }
      } else {
        for (int c = 0; c < DZ; ++c) a += Wz[h * DZ + c] * ln_b[c];
      }
      s12[t] = a;
    }
    return;
  }
  const int seg = blockIdx.y;
  const float* src;
  unsigned short* dh;
  unsigned short* dl = nullptr;
  int n;
  if (seg == 0) { src = s; dh = s_hi; n = S * D; }
  else {
    src = (seg == 1) ? Wq : (seg == 2) ? Wk : (seg == 3) ? Wv : (seg == 4) ? Wg : Wo;
    dh = w_hi + (size_t)(seg - 1) * D * D;
    if (seg == 5) dl = w_lo;     // only Wo keeps a lo plane
    n = D * D;
  }
  const int i4 = blockIdx.x * 256 + threadIdx.x;
  if (i4 * 4 < n) {
    const float4 v = *reinterpret_cast<const float4*>(src + (size_t)i4 * 4);
    ushort4 hh, ll;
    split2(v.x, hh.x, ll.x); split2(v.y, hh.y, ll.y);
    split2(v.z, hh.z, ll.z); split2(v.w, hh.w, ll.w);
    *reinterpret_cast<ushort4*>(dh + (size_t)i4 * 4) = hh;
    if (dl) *reinterpret_cast<ushort4*>(dl + (size_t)i4 * 4) = ll;
  }
}

// ---------------------------------------------------------------------------
// Plain-bf16 MFMA GEMM core over K range (32x32 tile/wave).
// ---------------------------------------------------------------------------
__device__ __forceinline__ void mfma_core32_bf(const unsigned short* __restrict__ Ah,
                                               const unsigned short* __restrict__ Wh,
                                               const int m0, const int n0,
                                               const int k0, const int k1,
                                               f32x4& a00, f32x4& a01, f32x4& a10, f32x4& a11) {
  const int lane = threadIdx.x & 63;
  const int r16 = lane & 15, kg = lane >> 4;
  const unsigned short* pah = Ah + (size_t)(m0 + r16) * D + kg * 8;
  const unsigned short* pbh = Wh + (size_t)(n0 + r16) * D + kg * 8;
#pragma unroll 2
  for (int k = k0; k < k1; k += 32) {
    const bf16x8 ah0 = *reinterpret_cast<const bf16x8*>(pah + k);
    const bf16x8 ah1 = *reinterpret_cast<const bf16x8*>(pah + 16 * D + k);
    const bf16x8 bh0 = *reinterpret_cast<const bf16x8*>(pbh + k);
    const bf16x8 bh1 = *reinterpret_cast<const bf16x8*>(pbh + 16 * D + k);
    a00 = __builtin_amdgcn_mfma_f32_16x16x32_bf16(ah0, bh0, a00, 0, 0, 0);
    a01 = __builtin_amdgcn_mfma_f32_16x16x32_bf16(ah0, bh1, a01, 0, 0, 0);
    a10 = __builtin_amdgcn_mfma_f32_16x16x32_bf16(ah1, bh0, a10, 0, 0, 0);
    a11 = __builtin_amdgcn_mfma_f32_16x16x32_bf16(ah1, bh1, a11, 0, 0, 0);
  }
}

// ===========================================================================
// qkvg (round-22 structure, unchanged): plain-bf16 core; q_hi/k_hi/vt_hi/g.
// ===========================================================================
__global__ __launch_bounds__(256)
void qkvg_mfma_kernel(const unsigned short* __restrict__ s_hi,
                      const unsigned short* __restrict__ w_hi,
                      const float* __restrict__ bq,
                      unsigned short* __restrict__ q_hi,
                      unsigned short* __restrict__ k_hi,
                      unsigned short* __restrict__ vt_hi,
                      float* __restrict__ g_ws) {
  __shared__ float TT[4][32 * 33];
  __shared__ float CB[2][64][17];
  const int wv = threadIdx.x >> 6;
  const int pair = wv >> 1;
  const int khalf = wv & 1;
  const int tileid = blockIdx.x * 2 + pair;   // 0..3071
  const int wsel = tileid / 768;
  const int rr = tileid % 768;
  const int m0 = (rr / 24) * 32, n0 = (rr % 24) * 32;
  f32x4 a00 = {0.f, 0.f, 0.f, 0.f}, a01 = a00, a10 = a00, a11 = a00;
  mfma_core32_bf(s_hi, w_hi + (size_t)wsel * D * D,
                 m0, n0, khalf * 384, khalf * 384 + 384, a00, a01, a10, a11);
  const int lane = threadIdx.x & 63;
  const int r16 = lane & 15, kg = lane >> 4;
  const float scale = 0.14433756729740643f;  // 1/sqrt(48)

  if (khalf == 1) {
#pragma unroll
    for (int r = 0; r < 4; ++r) {
      CB[pair][lane][r] = a00[r];
      CB[pair][lane][4 + r] = a01[r];
      CB[pair][lane][8 + r] = a10[r];
      CB[pair][lane][12 + r] = a11[r];
    }
  }
  __syncthreads();
  if (khalf == 1) return;
#pragma unroll
  for (int r = 0; r < 4; ++r) {
    a00[r] += CB[pair][lane][r];
    a01[r] += CB[pair][lane][4 + r];
    a10[r] += CB[pair][lane][8 + r];
    a11[r] += CB[pair][lane][12 + r];
  }

  float* T = TT[wv];
#pragma unroll
  for (int r = 0; r < 4; ++r) {
    T[(kg * 4 + r) * 33 + r16] = a00[r];
    T[(kg * 4 + r) * 33 + 16 + r16] = a01[r];
    T[(16 + kg * 4 + r) * 33 + r16] = a10[r];
    T[(16 + kg * 4 + r) * 33 + 16 + r16] = a11[r];
  }
  const int rr2 = lane >> 1, run = lane & 1;
  if (wsel <= 1) {
    const int row = m0 + rr2;
    const int col0 = n0 + run * 16;
    const int hcol0 = (col0 / 48) * 64 + (col0 % 48);
    unsigned short* dh = (wsel == 0) ? q_hi : k_hi;
#pragma unroll
    for (int p4 = 0; p4 < 4; ++p4) {
      float v0 = T[rr2 * 33 + run * 16 + p4 * 4 + 0];
      float v1 = T[rr2 * 33 + run * 16 + p4 * 4 + 1];
      float v2 = T[rr2 * 33 + run * 16 + p4 * 4 + 2];
      float v3 = T[rr2 * 33 + run * 16 + p4 * 4 + 3];
      if (wsel == 0) {
        v0 = (v0 + bq[col0 + p4 * 4 + 0]) * scale;
        v1 = (v1 + bq[col0 + p4 * 4 + 1]) * scale;
        v2 = (v2 + bq[col0 + p4 * 4 + 2]) * scale;
        v3 = (v3 + bq[col0 + p4 * 4 + 3]) * scale;
      }
      uint2 uh;
      uh.x = pack2(f2b(v0), f2b(v1)); uh.y = pack2(f2b(v2), f2b(v3));
      *reinterpret_cast<uint2*>(dh + (size_t)row * 1024 + hcol0 + p4 * 4) = uh;
    }
  } else if (wsel == 2) {
    const int c = lane >> 1;
    const int run2 = lane & 1;
    const int vc = n0 + c;
#pragma unroll
    for (int p4 = 0; p4 < 4; ++p4) {
      uint2 uh;
      uh.x = pack2(f2b(T[(run2 * 16 + p4 * 4 + 0) * 33 + c]),
                   f2b(T[(run2 * 16 + p4 * 4 + 1) * 33 + c]));
      uh.y = pack2(f2b(T[(run2 * 16 + p4 * 4 + 2) * 33 + c]),
                   f2b(T[(run2 * 16 + p4 * 4 + 3) * 33 + c]));
      *reinterpret_cast<uint2*>(vt_hi + (size_t)vc * 1024 + m0 + run2 * 16 + p4 * 4) = uh;
    }
  } else {
    const int row = m0 + rr2;
#pragma unroll
    for (int p4 = 0; p4 < 4; ++p4) {
      float4 v4;
      v4.x = T[rr2 * 33 + run * 16 + p4 * 4 + 0];
      v4.y = T[rr2 * 33 + run * 16 + p4 * 4 + 1];
      v4.z = T[rr2 * 33 + run * 16 + p4 * 4 + 2];
      v4.w = T[rr2 * 33 + run * 16 + p4 * 4 + 3];
      *reinterpret_cast<float4*>(g_ws + (size_t)row * D + n0 + run * 16 + p4 * 4) = v4;
    }
  }
}

// ---------------------------------------------------------------------------
// pair_bias v10: unchanged compute; bias output now bf16 (halves write
// traffic here and read traffic in attn — largest remaining stream).
// ---------------------------------------------------------------------------
__global__ __launch_bounds__(256)
void pair_bias_kernel(const float* __restrict__ z, const unsigned short* __restrict__ wzwb,
                      const float* __restrict__ s12, unsigned short* __restrict__ bias_out) {
  __shared__ float T[4][64 * 17];
  const int tid = threadIdx.x;
  const int lane = tid & 63;
  const int wv = tid >> 6;
  const int hq = lane & 15;
  const int grp = lane >> 4;

  bf16x8 bf[4];
#pragma unroll
  for (int m = 0; m < 4; ++m)
    bf[m] = *reinterpret_cast<const bf16x8*>(wzwb + hq * DZ + m * 32 + grp * 8);
  const float S1h = s12[hq], S2h = s12[16 + hq];

  const int chunk = blockIdx.x * 4 + wv;
  const size_t p0 = (size_t)chunk * 64;
  float* Tw = &T[wv][0];

#pragma unroll 1
  for (int sub = 0; sub < 4; ++sub) {
    const float* zr = z + (p0 + sub * 16 + hq) * DZ + grp * 8;
    f32x4 acc = {0.f, 0.f, 0.f, 0.f};
    float s1 = 0.f, s2 = 0.f;
#pragma unroll
    for (int m = 0; m < 4; ++m) {
      const float4 a0 = *reinterpret_cast<const float4*>(zr + m * 32);
      const float4 a1 = *reinterpret_cast<const float4*>(zr + m * 32 + 4);
      s1 += (a0.x + a0.y) + (a0.z + a0.w) + (a1.x + a1.y) + (a1.z + a1.w);
      s2 = fmaf(a0.x, a0.x, fmaf(a0.y, a0.y, fmaf(a0.z, a0.z, fmaf(a0.w, a0.w, s2))));
      s2 = fmaf(a1.x, a1.x, fmaf(a1.y, a1.y, fmaf(a1.z, a1.z, fmaf(a1.w, a1.w, s2))));
      bf16x8 af;
      af[0] = (short)f2b(a0.x); af[1] = (short)f2b(a0.y);
      af[2] = (short)f2b(a0.z); af[3] = (short)f2b(a0.w);
      af[4] = (short)f2b(a1.x); af[5] = (short)f2b(a1.y);
      af[6] = (short)f2b(a1.z); af[7] = (short)f2b(a1.w);
      acc = __builtin_amdgcn_mfma_f32_16x16x32_bf16(af, bf[m], acc, 0, 0, 0);
    }
    s1 += __shfl_xor(s1, 16); s1 += __shfl_xor(s1, 32);
    s2 += __shfl_xor(s2, 16); s2 += __shfl_xor(s2, 32);
    const float mu = s1 * (1.f / DZ);
    const float inv = rsqrtf(s2 * (1.f / DZ) - mu * mu + EPS);
#pragma unroll
    for (int r = 0; r < 4; ++r) {
      const int st = grp * 4 + r;
      const float mur = __shfl(mu, st);
      const float invr = __shfl(inv, st);
      Tw[(sub * 16 + st) * 17 + hq] = invr * (acc[r] - mur * S1h) + S2h;
    }
  }
#pragma unroll
  for (int hh = 0; hh < 16; ++hh)
    bias_out[(size_t)hh * S * S + p0 + lane] = f2b(Tw[lane * 17 + hh]);
}

// ===========================================================================
// Attention v7: QK^T hi-only; bias read as bf16 (converted to the MFMA C
// operand); PV = P_hi x V_hi (1 MFMA per (c,ds), Pl slab removed). a_hi out.
// Intra-block KV-split with fused reduce.
// ===========================================================================
constexpr int PST = 72;   // P slab stride (u16)
constexpr int PRS = 52;   // partial-result row stride (f32)

__global__ __launch_bounds__(256)
void attn_kernel(const unsigned short* __restrict__ q_hi,
                 const unsigned short* __restrict__ k_hi,
                 const unsigned short* __restrict__ vt_hi,
                 const unsigned short* __restrict__ bias, const float* __restrict__ g,
                 unsigned short* __restrict__ a_hi) {
  __shared__ unsigned short Ph[4][16 * PST];
  __shared__ float Pr[4][16 * PRS];
  const int lane = threadIdx.x & 63;
  const int wv = threadIdx.x >> 6;
  const int h = blockIdx.x >> 6;
  const int qb = blockIdx.x & 63;
  const int q0 = qb << 4;
  const int n16 = lane & 15, kg = lane >> 4;

  const size_t qbase = (size_t)(q0 + n16) * 1024 + h * 64;
  const bf16x8 qh0 = *reinterpret_cast<const bf16x8*>(q_hi + qbase + kg * 8);
  const bf16x8 qh1 = *reinterpret_cast<const bf16x8*>(q_hi + qbase + 32 + kg * 8);

  float mrow = -1e30f, lrow = 0.f;
  f32x4 accO[3] = {};
  unsigned short* php = Ph[wv];

#pragma unroll 1
  for (int t0 = wv * 256; t0 < wv * 256 + 256; t0 += 64) {
    f32x4 sc[4];
#pragma unroll
    for (int ts = 0; ts < 4; ++ts) {
      const size_t kb = (size_t)(t0 + ts * 16 + n16) * 1024 + h * 64;
      const bf16x8 kh0 = *reinterpret_cast<const bf16x8*>(k_hi + kb + kg * 8);
      const bf16x8 kh1 = *reinterpret_cast<const bf16x8*>(k_hi + kb + 32 + kg * 8);
      const ushort4 b4 = *reinterpret_cast<const ushort4*>(
          bias + (size_t)h * S * S + (size_t)(q0 + n16) * S + t0 + ts * 16 + kg * 4);
      f32x4 a;
      a[0] = b2f(b4.x); a[1] = b2f(b4.y); a[2] = b2f(b4.z); a[3] = b2f(b4.w);
      a = __builtin_amdgcn_mfma_f32_16x16x32_bf16(kh0, qh0, a, 0, 0, 0);
      a = __builtin_amdgcn_mfma_f32_16x16x32_bf16(kh1, qh1, a, 0, 0, 0);
      sc[ts] = a;
    }

    float tmax = sc[0][0];
#pragma unroll
    for (int ts = 0; ts < 4; ++ts)
#pragma unroll
      for (int r = 0; r < 4; ++r) tmax = fmaxf(tmax, sc[ts][r]);
    tmax = fmaxf(tmax, __shfl_xor(tmax, 16));
    tmax = fmaxf(tmax, __shfl_xor(tmax, 32));
    const float mn = fmaxf(mrow, tmax);
    const float fac = __expf(mrow - mn);
    mrow = mn;
    float psum = 0.f;
#pragma unroll
    for (int ts = 0; ts < 4; ++ts) {
      const float p0_ = __expf(sc[ts][0] - mn), p1_ = __expf(sc[ts][1] - mn);
      const float p2_ = __expf(sc[ts][2] - mn), p3_ = __expf(sc[ts][3] - mn);
      psum += (p0_ + p1_) + (p2_ + p3_);
      const int ti = ts * 16 + kg * 4;
      unsigned* wh = reinterpret_cast<unsigned*>(&php[n16 * PST + ti]);
      wh[0] = pack2(f2b(p0_), f2b(p1_));
      wh[1] = pack2(f2b(p2_), f2b(p3_));
    }
    lrow = lrow * fac + psum;

    float facr[4];
#pragma unroll
    for (int r = 0; r < 4; ++r) facr[r] = __shfl(fac, kg * 4 + r);
#pragma unroll
    for (int ds = 0; ds < 3; ++ds)
#pragma unroll
      for (int r = 0; r < 4; ++r) accO[ds][r] *= facr[r];

#pragma unroll
    for (int c = 0; c < 2; ++c) {
      const bf16x8 pah = *reinterpret_cast<const bf16x8*>(&php[n16 * PST + c * 32 + kg * 8]);
#pragma unroll
      for (int ds = 0; ds < 3; ++ds) {
        const size_t vb = (size_t)(h * 48 + ds * 16 + n16) * 1024 + t0 + c * 32 + kg * 8;
        const bf16x8 vh = *reinterpret_cast<const bf16x8*>(vt_hi + vb);
        accO[ds] = __builtin_amdgcn_mfma_f32_16x16x32_bf16(pah, vh, accO[ds], 0, 0, 0);
      }
    }
  }

  lrow += __shfl_xor(lrow, 16);
  lrow += __shfl_xor(lrow, 32);

  float* pw = Pr[wv];
#pragma unroll
  for (int ds = 0; ds < 3; ++ds)
#pragma unroll
    for (int r = 0; r < 4; ++r)
      pw[(kg * 4 + r) * PRS + ds * 16 + n16] = accO[ds][r];
  if (kg == 0) {
    pw[n16 * PRS + 48] = mrow;
    pw[n16 * PRS + 49] = lrow;
  }
  __syncthreads();

  const int row = threadIdx.x >> 4;
  const int dsub = threadIdx.x & 15;
  const float m0_ = Pr[0][row * PRS + 48], m1_ = Pr[1][row * PRS + 48];
  const float m2_ = Pr[2][row * PRS + 48], m3_ = Pr[3][row * PRS + 48];
  const float l0_ = Pr[0][row * PRS + 49], l1_ = Pr[1][row * PRS + 49];
  const float l2_ = Pr[2][row * PRS + 49], l3_ = Pr[3][row * PRS + 49];
  const float M = fmaxf(fmaxf(m0_, m1_), fmaxf(m2_, m3_));
  const float e0 = __expf(m0_ - M), e1 = __expf(m1_ - M);
  const float e2 = __expf(m2_ - M), e3 = __expf(m3_ - M);
  const float rl = 1.f / (l0_ * e0 + l1_ * e1 + l2_ * e2 + l3_ * e3);
#pragma unroll
  for (int j = 0; j < 3; ++j) {
    const int d = dsub * 3 + j;
    const float o = (Pr[0][row * PRS + d] * e0 + Pr[1][row * PRS + d] * e1 +
                     Pr[2][row * PRS + d] * e2 + Pr[3][row * PRS + d] * e3) * rl;
    const size_t idx = (size_t)(q0 + row) * D + h * 48 + d;
    const float a = o * sigmoidf_(g[idx]);
    a_hi[idx] = f2b(a);
  }
}

// ===========================================================================
// outproj (round-22 structure, unchanged): a_hi x (Wo_hi + Wo_lo), split-K x2.
// ===========================================================================
__global__ __launch_bounds__(256)
void outproj_mfma_kernel(const unsigned short* __restrict__ a_hi,
                         const unsigned short* __restrict__ wo_hi,
                         const unsigned short* __restrict__ wo_lo,
                         float* __restrict__ out) {
  __shared__ float CB[2][64][9];
  const int wv = threadIdx.x >> 6;
  const int pair = wv >> 1;
  const int khalf = wv & 1;
  const int tileid = blockIdx.x * 2 + pair;   // 0..1535
  const int m0 = (tileid / 48) * 32, n0 = (tileid % 48) * 16;
  const int lane = threadIdx.x & 63;
  const int r16 = lane & 15, kg = lane >> 4;
  const unsigned short* pah = a_hi + (size_t)(m0 + r16) * D + kg * 8;
  const unsigned short* pbh = wo_hi + (size_t)(n0 + r16) * D + kg * 8;
  const unsigned short* pbl = wo_lo + (size_t)(n0 + r16) * D + kg * 8;
  f32x4 a0 = {0.f, 0.f, 0.f, 0.f}, a1 = a0;
#pragma unroll 2
  for (int k = khalf * 384; k < khalf * 384 + 384; k += 32) {
    const bf16x8 ah0 = *reinterpret_cast<const bf16x8*>(pah + k);
    const bf16x8 ah1 = *reinterpret_cast<const bf16x8*>(pah + 16 * D + k);
    const bf16x8 bh0 = *reinterpret_cast<const bf16x8*>(pbh + k);
    const bf16x8 bl0 = *reinterpret_cast<const bf16x8*>(pbl + k);
    a0 = __builtin_amdgcn_mfma_f32_16x16x32_bf16(ah0, bh0, a0, 0, 0, 0);
    a0 = __builtin_amdgcn_mfma_f32_16x16x32_bf16(ah0, bl0, a0, 0, 0, 0);
    a1 = __builtin_amdgcn_mfma_f32_16x16x32_bf16(ah1, bh0, a1, 0, 0, 0);
    a1 = __builtin_amdgcn_mfma_f32_16x16x32_bf16(ah1, bl0, a1, 0, 0, 0);
  }
  if (khalf == 1) {
#pragma unroll
    for (int r = 0; r < 4; ++r) {
      CB[pair][lane][r] = a0[r];
      CB[pair][lane][4 + r] = a1[r];
    }
  }
  __syncthreads();
  if (khalf == 1) return;
#pragma unroll
  for (int r = 0; r < 4; ++r) {
    a0[r] += CB[pair][lane][r];
    a1[r] += CB[pair][lane][4 + r];
  }
#pragma unroll
  for (int r = 0; r < 4; ++r) {
    out[(size_t)(m0 + kg * 4 + r) * D + n0 + r16] = a0[r];
    out[(size_t)(m0 + 16 + kg * 4 + r) * D + n0 + r16] = a1[r];
  }
}

extern "C" void kernel_launch(void* const* d_in, const int* in_sizes, int n_in,
                              void* d_out, int out_size, void* d_ws, size_t ws_size,
                              hipStream_t stream) {
  const float* s    = (const float*)d_in[0];
  const float* z    = (const float*)d_in[1];
  const float* Wq   = (const float*)d_in[2];
  const float* bq   = (const float*)d_in[3];
  const float* Wk   = (const float*)d_in[4];
  const float* Wv   = (const float*)d_in[5];
  const float* Wg   = (const float*)d_in[6];
  const float* ln_w = (const float*)d_in[7];
  const float* ln_b = (const float*)d_in[8];
  const float* Wz   = (const float*)d_in[9];
  const float* Wo   = (const float*)d_in[10];
  float* out = (float*)d_out;

  float* g_ws    = (float*)d_ws;                                  // S*D f32
  float* s12_ws  = g_ws + (size_t)S * D;                          // 32 f32
  unsigned short* bias16 = (unsigned short*)(s12_ws + 32);        // H*S*S u16 (bf16)
  unsigned short* wzwb_ws = bias16 + (size_t)H * S * S;           // 2048 u16
  unsigned short* s_hi = wzwb_ws + 2048;                          // S*D
  unsigned short* w_hi = s_hi + (size_t)S * D;                    // 5*D*D
  unsigned short* wo_lo = w_hi + (size_t)5 * D * D;               // D*D (Wo lo)
  unsigned short* a_hi = wo_lo + (size_t)D * D;                   // S*D
  unsigned short* q_hi = a_hi + (size_t)S * D;                    // [S][1024] padded
  unsigned short* k_hi = q_hi + (size_t)S * 1024;
  unsigned short* vt_hi = k_hi + (size_t)S * 1024;                // [768][1024]

  // A) splits (hi-only except Wo) + pb_prep + padzero
  prep_kernel<<<dim3(812, 6), 256, 0, stream>>>(s, Wq, Wk, Wv, Wg, Wo,
                                                s_hi, w_hi, wo_lo,
                                                Wz, ln_w, ln_b, wzwb_ws, s12_ws,
                                                q_hi, k_hi);
  // B) qkvg (plain bf16, split-K x2) + pair_bias (bf16 bias out)
  qkvg_mfma_kernel<<<1536, 256, 0, stream>>>(s_hi, w_hi, bq,
                                             q_hi, k_hi, vt_hi, g_ws);
  pair_bias_kernel<<<4096, 256, 0, stream>>>(z, wzwb_ws, s12_ws, bias16);
  // C) fused KV-split attention (QK hi; bias bf16; PV hi-only; gate fused)
  attn_kernel<<<1024, 256, 0, stream>>>(q_hi, k_hi, vt_hi,
                                        bias16, g_ws, a_hi);
  // D) output projection (a hi x Wo split)
  outproj_mfma_kernel<<<768, 256, 0, stream>>>(a_hi, w_hi + (size_t)4 * D * D,
                                               wo_lo, out);
}